// Round 1
// 1121.926 us; speedup vs baseline: 1.2207x; 1.2207x over previous
//
#include <hip/hip_runtime.h>

typedef unsigned short u16;
typedef __attribute__((ext_vector_type(8))) short bf16x8;   // 8 x bf16 bits
typedef __attribute__((ext_vector_type(4))) float floatx4;

#define NSPOT 20000
#define NGENE 3000
#define E1N   640000
#define E2N   320000

// output element offsets (res, lam, h2, h4 concatenated)
#define OFF_RES 0
#define OFF_LAM 5120000
#define OFF_H2  5160000
#define OFF_H4  5480000

__device__ __forceinline__ float b2f(u16 u){
  union { unsigned int i; float f; } v; v.i = ((unsigned int)u) << 16; return v.f;
}
__device__ __forceinline__ u16 f2b(float f){
  union { float f; unsigned int i; } v; v.f = f;
  unsigned int i = v.i;
  return (u16)((i + 0x7FFFu + ((i >> 16) & 1u)) >> 16);
}
__device__ __forceinline__ void stout(void* O, size_t i, float v, int isbf){
  if (isbf) ((u16*)O)[i] = f2b(v); else ((float*)O)[i] = v;
}
__device__ __forceinline__ u16 ldu(const void* p, size_t i, int isbf){
  return isbf ? ((const u16*)p)[i] : f2b(((const float*)p)[i]);
}

// ---------------- dtype sniffer ----------------
__global__ void sniff_kernel(const u16* __restrict__ x, int* __restrict__ flag){
  int lane = threadIdx.x;
  u16 u = x[lane * 2];
  int e = (u >> 7) & 0xFF;
  int sane = (u == 0) || (e >= 0x60 && e <= 0xA0);
  unsigned long long b = __ballot(sane);
  if (lane == 0) flag[0] = (__popcll(b) >= 48) ? 1 : 0;
}

// ---------------- batched small-param convert ----------------
struct ConvSeg { const void* src; u16* dst; int n; };
struct ConvBatch { ConvSeg s[14]; };
__global__ void convbatch_kernel(ConvBatch cb, const int* __restrict__ dflag){
  ConvSeg S = cb.s[blockIdx.y];
  int i = blockIdx.x * 256 + threadIdx.x;
  if (i < S.n) S.dst[i] = ldu(S.src, i, dflag[0]);
}

// vectorized convert (n multiple of 4)
__global__ void conv4_kernel(const void* __restrict__ src, u16* __restrict__ dst, int n4,
                             const int* __restrict__ dflag){
  int i = blockIdx.x * 256 + threadIdx.x;
  if (i >= n4) return;
  size_t b = (size_t)i * 4;
  u16 o[4];
  if (dflag[0]){
    *(uint2*)o = *(const uint2*)((const u16*)src + b);
  } else {
    float4 f = *(const float4*)((const float*)src + b);
    o[0]=f2b(f.x); o[1]=f2b(f.y); o[2]=f2b(f.z); o[3]=f2b(f.w);
  }
  *(uint2*)(dst + b) = *(uint2*)o;
}

// ---------------- transpose GE[K][M] -> AT[M][K] bf16 (K%8==0 rows, guards inside) ----
__global__ __launch_bounds__(256) void transpose_kernel(
    const void* __restrict__ GE, u16* __restrict__ AT,
    const int* __restrict__ dflag, int K, int M){
  __shared__ float tile[64 * 65];
  int isbf = dflag[0];
  int m0 = blockIdx.x * 64, k0 = blockIdx.y * 64;
#pragma unroll
  for (int i = 0; i < 4; i++){
    int idx = threadIdx.x + i * 256;
    int kr = idx >> 4, mc = (idx & 15) * 4;
    int gk = k0 + kr, gm = m0 + mc;
    if (gk < K){
      float v0 = 0.f, v1 = 0.f, v2 = 0.f, v3 = 0.f;
      if (gm + 4 <= M){
        if (isbf){
          const u16* pp = (const u16*)GE + (size_t)gk * M + gm;
          v0 = b2f(pp[0]); v1 = b2f(pp[1]); v2 = b2f(pp[2]); v3 = b2f(pp[3]);
        } else {
          float4 f = *(const float4*)((const float*)GE + (size_t)gk * M + gm);
          v0 = f.x; v1 = f.y; v2 = f.z; v3 = f.w;
        }
      } else {
        for (int e = 0; e < 4; e++){
          if (gm + e < M){
            float t = isbf ? b2f(((const u16*)GE)[(size_t)gk * M + gm + e])
                           : ((const float*)GE)[(size_t)gk * M + gm + e];
            if (e == 0) v0 = t; else if (e == 1) v1 = t; else if (e == 2) v2 = t; else v3 = t;
          }
        }
      }
      tile[(mc + 0) * 65 + kr] = v0;
      tile[(mc + 1) * 65 + kr] = v1;
      tile[(mc + 2) * 65 + kr] = v2;
      tile[(mc + 3) * 65 + kr] = v3;
    }
  }
  __syncthreads();
#pragma unroll
  for (int i = 0; i < 2; i++){
    int idx = threadIdx.x + i * 256;
    int mr = idx >> 3, kc = (idx & 7) * 8;
    int gm = m0 + mr, gk = k0 + kc;
    if (gm < M && gk < K){
      if (gk + 8 <= K){
        u16 o[8];
#pragma unroll
        for (int e = 0; e < 8; e++) o[e] = f2b(tile[mr * 65 + kc + e]);
        *(uint4*)&AT[(size_t)gm * K + gk] = *(uint4*)o;
      } else {
        for (int e = 0; e < 8 && gk + e < K; e++)
          AT[(size_t)gm * K + gk + e] = f2b(tile[mr * 65 + kc + e]);
      }
    }
  }
}

// ---------------- CSR build ----------------
__global__ void hist_kernel(const int* __restrict__ dst, int* __restrict__ cnt, int E){
  int e = blockIdx.x * 256 + threadIdx.x;
  if (e < E){ int d = dst[e]; if ((unsigned)d < (unsigned)NSPOT) atomicAdd(&cnt[d], 1); }
}

__global__ void scan_kernel(const int* __restrict__ cnt, int* __restrict__ off,
                            int* __restrict__ cur, int n){
  __shared__ int part[256];
  int tid = threadIdx.x;
  int chunk = (n + 255) / 256;
  int lo = tid * chunk; if (lo > n) lo = n;
  int hi = lo + chunk; if (hi > n) hi = n;
  int s = 0;
  for (int i = lo; i < hi; i++) s += cnt[i];
  part[tid] = s;
  __syncthreads();
  if (tid == 0){
    int run = 0;
    for (int i = 0; i < 256; i++){ int t = part[i]; part[i] = run; run += t; }
  }
  __syncthreads();
  int run = part[tid];
  for (int i = lo; i < hi; i++){ off[i] = run; cur[i] = run; run += cnt[i]; }
  if (hi == n) off[n] = run;
}

__global__ void scatter_kernel(const int* __restrict__ src, const int* __restrict__ dst,
                               int* __restrict__ cur, int* __restrict__ out, int E){
  int e = blockIdx.x * 256 + threadIdx.x;
  if (e < E){
    int d = dst[e];
    if ((unsigned)d < (unsigned)NSPOT){
      int p = atomicAdd(&cur[d], 1);
      if ((unsigned)p < (unsigned)E) out[p] = src[e];
    }
  }
}

// ---------------- weight concat ----------------
__global__ void assemble_kernel(const void* Wl, const void* bl, const void* Wr, const void* br,
                                const void* Wlp, const void* blp, const void* Wrp, const void* brp,
                                u16* __restrict__ Wcat, u16* __restrict__ bcat, int Kdim,
                                const int* __restrict__ dflag){
  int isbf = dflag[0];
  int idx = blockIdx.x * 256 + threadIdx.x;
  int total = Kdim * 768;
  if (idx < total){
    int k = idx / 768, j = idx % 768;
    int seg = j / 192, jj = j % 192;
    const void* W = (seg == 0) ? Wl : (seg == 1) ? Wr : (seg == 2) ? Wlp : Wrp;
    Wcat[idx] = ldu(W, (size_t)k * 192 + jj, isbf);
  }
  if (idx < 768){
    int seg = idx / 192, jj = idx % 192;
    const void* b = (seg == 0) ? bl : (seg == 1) ? br : (seg == 2) ? blp : brp;
    bcat[idx] = ldu(b, jj, isbf);
  }
}

// ---------------- MFMA GEMM (BM = 64*BMI, BN=64) ----------------
template<int BMI, bool A_KM, bool B_NK, bool A_EXT, bool B_EXT, bool RELU, bool HAS_BIAS, bool C_OUT>
__global__ __launch_bounds__(256) void gemm_mfma(
    const void* __restrict__ A, const void* __restrict__ B,
    const u16* __restrict__ bias, void* __restrict__ Cp,
    const int* __restrict__ dflag, size_t aoff, size_t coff,
    int M, int N, int K, int lda, int ldb, int ldc)
{
  const int isbf = dflag[0];
  constexpr int BM = 64 * BMI, BK = 32, LDA = BK + 8, LDB = BK + 8;
  __shared__ __align__(16) u16 As[BM * LDA];
  __shared__ __align__(16) u16 Bs[64 * LDB];
  const u16*   A16 = (const u16*)A + aoff;
  const float* A32 = (const float*)A + aoff;
  const u16*   B16 = (const u16*)B;
  const float* B32 = (const float*)B;
  auto ldA = [&](size_t i) -> u16 { return (!A_EXT || isbf) ? A16[i] : f2b(A32[i]); };
  auto ldB = [&](size_t i) -> u16 { return (!B_EXT || isbf) ? B16[i] : f2b(B32[i]); };

  int tid = threadIdx.x;
  int lane = tid & 63, w = tid >> 6;
  int m0 = blockIdx.y * BM, n0 = blockIdx.x * 64;
  floatx4 acc[BMI][4] = {};
  int quad = lane >> 4;
  int nk = (K + BK - 1) / BK;
  for (int kt = 0; kt < nk; kt++){
    int k0 = kt * BK;
    // ---- stage A -> As[m][k] ----
    if (!A_KM){
#pragma unroll
      for (int i = 0; i < BMI; i++){
        int id = tid + i * 256;
        int r = id >> 2, c = (id & 3) * 8;
        int gm = m0 + r, gk = k0 + c;
        if (gm < M && gk + 8 <= K){
          if (!A_EXT || isbf){
            *(uint4*)&As[r * LDA + c] = *(const uint4*)(A16 + (size_t)gm * lda + gk);
          } else {
            const float* p = A32 + (size_t)gm * lda + gk;
            float4 f0 = *(const float4*)p, f1 = *(const float4*)(p + 4);
            u16* d = &As[r * LDA + c];
            d[0]=f2b(f0.x); d[1]=f2b(f0.y); d[2]=f2b(f0.z); d[3]=f2b(f0.w);
            d[4]=f2b(f1.x); d[5]=f2b(f1.y); d[6]=f2b(f1.z); d[7]=f2b(f1.w);
          }
        } else {
          for (int e = 0; e < 8; e++)
            As[r * LDA + c + e] = (gm < M && gk + e < K) ? ldA((size_t)gm * lda + gk + e) : (u16)0;
        }
      }
    } else {
#pragma unroll
      for (int i = 0; i < BMI; i++){
        int id = tid + i * 256;
        int kk, rr;
        if (BMI == 2){ kk = id >> 4; rr = (id & 15) * 8; }
        else         { kk = id >> 3; rr = (id & 7) * 8; }
        int gk = k0 + kk, gm = m0 + rr;
        if (gk < K && gm + 8 <= M){
          if (!A_EXT || isbf){
            uint4 v = *(const uint4*)(A16 + (size_t)gk * lda + gm);
            const u16* pv = (const u16*)&v;
#pragma unroll
            for (int e = 0; e < 8; e++) As[(rr + e) * LDA + kk] = pv[e];
          } else {
            const float* p = A32 + (size_t)gk * lda + gm;
            float4 f0 = *(const float4*)p, f1 = *(const float4*)(p + 4);
            As[(rr+0)*LDA+kk]=f2b(f0.x); As[(rr+1)*LDA+kk]=f2b(f0.y);
            As[(rr+2)*LDA+kk]=f2b(f0.z); As[(rr+3)*LDA+kk]=f2b(f0.w);
            As[(rr+4)*LDA+kk]=f2b(f1.x); As[(rr+5)*LDA+kk]=f2b(f1.y);
            As[(rr+6)*LDA+kk]=f2b(f1.z); As[(rr+7)*LDA+kk]=f2b(f1.w);
          }
        } else {
          for (int e = 0; e < 8; e++)
            As[(rr + e) * LDA + kk] = (gk < K && gm + e < M) ? ldA((size_t)gk * lda + gm + e) : (u16)0;
        }
      }
    }
    // ---- stage B -> Bs[n][k] ----
    if (B_NK){
      int r = tid >> 2, c = (tid & 3) * 8;
      int gn = n0 + r, gk = k0 + c;
      if (gn < N && gk + 8 <= K){
        if (!B_EXT || isbf){
          *(uint4*)&Bs[r * LDB + c] = *(const uint4*)(B16 + (size_t)gn * ldb + gk);
        } else {
          const float* p = B32 + (size_t)gn * ldb + gk;
          float4 f0 = *(const float4*)p, f1 = *(const float4*)(p + 4);
          u16* d = &Bs[r * LDB + c];
          d[0]=f2b(f0.x); d[1]=f2b(f0.y); d[2]=f2b(f0.z); d[3]=f2b(f0.w);
          d[4]=f2b(f1.x); d[5]=f2b(f1.y); d[6]=f2b(f1.z); d[7]=f2b(f1.w);
        }
      } else {
        for (int e = 0; e < 8; e++)
          Bs[r * LDB + c + e] = (gn < N && gk + e < K) ? ldB((size_t)gn * ldb + gk + e) : (u16)0;
      }
    } else {
      int kk = tid >> 3, nn = (tid & 7) * 8;
      int gk = k0 + kk, gn = n0 + nn;
      if (gk < K && gn + 8 <= N){
        if (!B_EXT || isbf){
          uint4 v = *(const uint4*)(B16 + (size_t)gk * ldb + gn);
          const u16* pv = (const u16*)&v;
#pragma unroll
          for (int e = 0; e < 8; e++) Bs[(nn + e) * LDB + kk] = pv[e];
        } else {
          const float* p = B32 + (size_t)gk * ldb + gn;
          float4 f0 = *(const float4*)p, f1 = *(const float4*)(p + 4);
          Bs[(nn+0)*LDB+kk]=f2b(f0.x); Bs[(nn+1)*LDB+kk]=f2b(f0.y);
          Bs[(nn+2)*LDB+kk]=f2b(f0.z); Bs[(nn+3)*LDB+kk]=f2b(f0.w);
          Bs[(nn+4)*LDB+kk]=f2b(f1.x); Bs[(nn+5)*LDB+kk]=f2b(f1.y);
          Bs[(nn+6)*LDB+kk]=f2b(f1.z); Bs[(nn+7)*LDB+kk]=f2b(f1.w);
        }
      } else {
        for (int e = 0; e < 8; e++)
          Bs[(nn + e) * LDB + kk] = (gk < K && gn + e < N) ? ldB((size_t)gk * ldb + gn + e) : (u16)0;
      }
    }
    __syncthreads();
    // ---- MFMA ----
    bf16x8 af[BMI];
#pragma unroll
    for (int mi = 0; mi < BMI; mi++)
      af[mi] = *(const bf16x8*)&As[(w * (16 * BMI) + mi * 16 + (lane & 15)) * LDA + quad * 8];
#pragma unroll
    for (int ni = 0; ni < 4; ni++){
      bf16x8 bfr = *(const bf16x8*)&Bs[(ni * 16 + (lane & 15)) * LDB + quad * 8];
#pragma unroll
      for (int mi = 0; mi < BMI; mi++)
        acc[mi][ni] = __builtin_amdgcn_mfma_f32_16x16x32_bf16(af[mi], bfr, acc[mi][ni], 0, 0, 0);
    }
    __syncthreads();
  }
  // ---- epilogue ----
#pragma unroll
  for (int mi = 0; mi < BMI; mi++)
#pragma unroll
    for (int ni = 0; ni < 4; ni++)
#pragma unroll
      for (int r = 0; r < 4; r++){
        int row = m0 + w * (16 * BMI) + mi * 16 + quad * 4 + r;
        int col = n0 + ni * 16 + (lane & 15);
        if (row < M && col < N){
          float v = acc[mi][ni][r];
          if (HAS_BIAS) v += b2f(bias[col]);
          if (RELU) v = fmaxf(v, 0.f);
          size_t ci = coff + (size_t)row * ldc + col;
          if (!C_OUT) ((u16*)Cp)[ci] = f2b(v);
          else stout(Cp, ci, v, isbf);
        }
      }
}

// ---------------- GATv2 aggregation: one wave per dst ----------------
// 4 edges per iteration, 16 lanes per edge (lane = sub*16 + c16, each lane
// owns 4 consecutive channels per head). Amortizes the score reduction
// (4 shfl steps over 16 lanes per 4 edges instead of 6 steps over 64 lanes
// per edge) and issues 4x fewer gather-load instructions for the same bytes.
__global__ __launch_bounds__(256) void gat_kernel(
    const u16* __restrict__ Y, int xl_off, int xr_off,
    const int* __restrict__ off, const int* __restrict__ srcs,
    const u16* __restrict__ att, const u16* __restrict__ bias,
    u16* __restrict__ aggout, int out_off, int n, int E)
{
  int wid = (blockIdx.x * 256 + threadIdx.x) >> 6;
  int lane = threadIdx.x & 63;
  if (wid >= n) return;
  int sub = lane >> 4;          // edge slot within chunk (0..3)
  int cbase = (lane & 15) * 4;  // 4 consecutive channels per head
  const int ldY = 768;
  size_t drow = (size_t)wid * ldY;

  // xr (dst transform) and att, loaded once per dst: 3 heads x 4 channels each
  float xr[3][4], at[3][4];
#pragma unroll
  for (int h = 0; h < 3; h++){
    uint2 vx = *(const uint2*)(Y + drow + xr_off + h * 64 + cbase);
    uint2 va = *(const uint2*)(att + h * 64 + cbase);
    const u16* px = (const u16*)&vx;
    const u16* pa = (const u16*)&va;
#pragma unroll
    for (int j = 0; j < 4; j++){ xr[h][j] = b2f(px[j]); at[h][j] = b2f(pa[j]); }
  }

  int beg = off[wid], end = off[wid + 1];
  beg = max(0, min(beg, E));
  end = max(beg, min(end, E));

  float mh[3] = {-INFINITY, -INFINITY, -INFINITY};
  float lh[3] = {0.f, 0.f, 0.f};
  float ac[3][4] = {};

  // prefetch: gather for chunk 0, src index for chunk 1
  uint2 xa[3] = {};
  int s_b = 0;
  if (beg < end){
    int e0 = beg + sub;
    int s = (e0 < end) ? srcs[e0] : 0;
    if ((unsigned)s >= (unsigned)NSPOT) s = 0;
    const u16* p = Y + (size_t)s * ldY + xl_off + cbase;
#pragma unroll
    for (int h = 0; h < 3; h++) xa[h] = *(const uint2*)(p + h * 64);
    if (beg + 4 < end){
      int e1 = beg + 4 + sub;
      int s1 = (e1 < end) ? srcs[e1] : 0;
      if ((unsigned)s1 >= (unsigned)NSPOT) s1 = 0;
      s_b = s1;
    }
  }

  for (int b = beg; b < end; b += 4){
    uint2 xc[3];
#pragma unroll
    for (int h = 0; h < 3; h++) xc[h] = xa[h];
    bool act = (b + sub) < end;

    // issue gather for chunk b+4 (index already resident), fetch index for b+8
    if (b + 4 < end){
      const u16* p = Y + (size_t)s_b * ldY + xl_off + cbase;
#pragma unroll
      for (int h = 0; h < 3; h++) xa[h] = *(const uint2*)(p + h * 64);
      if (b + 8 < end){
        int e2 = b + 8 + sub;
        int s2 = (e2 < end) ? srcs[e2] : 0;
        if ((unsigned)s2 >= (unsigned)NSPOT) s2 = 0;
        s_b = s2;
      }
    }

    // partial leaky-dot per lane (4 channels x 3 heads)
    float xl[3][4];
    float t0, t1, t2;
    {
      float a0 = 0.f, a1 = 0.f, a2 = 0.f;
      const u16* p0 = (const u16*)&xc[0];
      const u16* p1 = (const u16*)&xc[1];
      const u16* p2 = (const u16*)&xc[2];
#pragma unroll
      for (int j = 0; j < 4; j++){
        float x0 = b2f(p0[j]); xl[0][j] = x0;
        float u0 = x0 + xr[0][j]; u0 = fmaxf(u0, 0.2f * u0);
        a0 = __builtin_fmaf(at[0][j], u0, a0);
        float x1 = b2f(p1[j]); xl[1][j] = x1;
        float u1 = x1 + xr[1][j]; u1 = fmaxf(u1, 0.2f * u1);
        a1 = __builtin_fmaf(at[1][j], u1, a1);
        float x2 = b2f(p2[j]); xl[2][j] = x2;
        float u2 = x2 + xr[2][j]; u2 = fmaxf(u2, 0.2f * u2);
        a2 = __builtin_fmaf(at[2][j], u2, a2);
      }
      t0 = a0; t1 = a1; t2 = a2;
    }
    // reduce within each 16-lane subgroup (4 steps, 3 heads interleaved)
#pragma unroll
    for (int d = 1; d < 16; d <<= 1){
      t0 += __shfl_xor(t0, d, 64);
      t1 += __shfl_xor(t1, d, 64);
      t2 += __shfl_xor(t2, d, 64);
    }
    if (act){
      float tt[3] = {t0, t1, t2};
#pragma unroll
      for (int h = 0; h < 3; h++){
        float nm = fmaxf(mh[h], tt[h]);
        if (nm > mh[h]){
          float sc = __expf(mh[h] - nm);   // exp(-inf)=0 on first edge
          lh[h] *= sc;
#pragma unroll
          for (int j = 0; j < 4; j++) ac[h][j] *= sc;
          mh[h] = nm;
        }
        float w = __expf(tt[h] - mh[h]);
        lh[h] += w;
#pragma unroll
        for (int j = 0; j < 4; j++) ac[h][j] = __builtin_fmaf(w, xl[h][j], ac[h][j]);
      }
    }
  }

  // combine the 4 subgroups' online-softmax states (xor 16, 32 butterfly)
  float o[4] = {0.f, 0.f, 0.f, 0.f};
#pragma unroll
  for (int h = 0; h < 3; h++){
    float gm = fmaxf(mh[h], __shfl_xor(mh[h], 16, 64));
    gm = fmaxf(gm, __shfl_xor(gm, 32, 64));
    float sc = (mh[h] == -INFINITY) ? 0.f : __expf(mh[h] - gm);
    float L = lh[h] * sc;
    L += __shfl_xor(L, 16, 64);
    L += __shfl_xor(L, 32, 64);
    float inv = 1.f / fmaxf(L, 1e-16f);
#pragma unroll
    for (int j = 0; j < 4; j++){
      float a = ac[h][j] * sc;
      a += __shfl_xor(a, 16, 64);
      a += __shfl_xor(a, 32, 64);
      o[j] += a * inv;
    }
  }
  if (sub == 0){
    u16 ov[4];
#pragma unroll
    for (int j = 0; j < 4; j++){
      float v = o[j] * (1.f / 3.f) + b2f(bias[cbase + j]);
      v = (v > 0.f) ? v : expm1f(v);
      if (!(fabsf(v) < 1e30f)) v = 0.f;
      ov[j] = f2b(v);
    }
    *(uint2*)&aggout[(size_t)wid * 128 + out_off + cbase] = *(uint2*)ov;
  }
}

// ---------------- h2 = h1 @ W2 + b2 ----------------
__global__ __launch_bounds__(256) void h2_kernel(const u16* __restrict__ AGG,
                                                 const u16* __restrict__ W2, const u16* __restrict__ b2,
                                                 float* __restrict__ H2, void* __restrict__ OUT,
                                                 const int* __restrict__ dflag, int n){
  __shared__ float w2s[128 * 16];
  __shared__ float as_[16][128];
  int isbf = dflag[0];
  int tid = threadIdx.x;
  for (int i = tid; i < 128 * 16; i += 256) w2s[i] = b2f(W2[i]);
  int m0 = blockIdx.x * 16;
  for (int i = tid; i < 16 * 128; i += 256){
    int r = i >> 7, c = i & 127; int m = m0 + r;
    as_[r][c] = (m < n) ? b2f(AGG[(size_t)m * 128 + c]) : 0.f;
  }
  __syncthreads();
  int r = tid >> 4, j = tid & 15;
  int m = m0 + r;
  float acc = b2f(b2[j]);
  for (int k = 0; k < 128; k++) acc += as_[r][k] * w2s[k * 16 + j];
  if (m < n){
    H2[(size_t)m * 16 + j] = acc;
    stout(OUT, (size_t)OFF_H2 + (size_t)m * 16 + j, acc, isbf);
  }
}

// ---------------- Y2 = h2 @ Wcat2 + bcat2 ----------------
__global__ __launch_bounds__(256) void y2_kernel(const float* __restrict__ H2,
                                                 const u16* __restrict__ Wcat2, const u16* __restrict__ bcat2,
                                                 u16* __restrict__ Y2, int n){
  __shared__ u16 ws_[16 * 768];
  __shared__ float h[16][16];
  int tid = threadIdx.x;
  for (int i = tid; i < 16 * 768; i += 256) ws_[i] = Wcat2[i];
  int m0 = blockIdx.x * 16;
  {
    int r = tid >> 4, k = tid & 15; int m = m0 + r;
    h[r][k] = (m < n) ? H2[(size_t)m * 16 + k] : 0.f;
  }
  __syncthreads();
  int j = tid;
  float acc[16][3];
  float bj0 = b2f(bcat2[j]), bj1 = b2f(bcat2[j + 256]), bj2 = b2f(bcat2[j + 512]);
#pragma unroll
  for (int r = 0; r < 16; r++){ acc[r][0] = bj0; acc[r][1] = bj1; acc[r][2] = bj2; }
  for (int k = 0; k < 16; k++){
    float w0 = b2f(ws_[k * 768 + j]);
    float w1 = b2f(ws_[k * 768 + j + 256]);
    float w2 = b2f(ws_[k * 768 + j + 512]);
#pragma unroll
    for (int r = 0; r < 16; r++){
      float hv = h[r][k];
      acc[r][0] += hv * w0; acc[r][1] += hv * w1; acc[r][2] += hv * w2;
    }
  }
#pragma unroll
  for (int r = 0; r < 16; r++){
    int m = m0 + r;
    if (m < n){
      size_t base = (size_t)m * 768;
      Y2[base + j] = f2b(acc[r][0]);
      Y2[base + j + 256] = f2b(acc[r][1]);
      Y2[base + j + 512] = f2b(acc[r][2]);
    }
  }
}

// ---------------- Cross attention (wave per row) ----------------
__global__ __launch_bounds__(256) void cross_attn_kernel(
    const u16* __restrict__ XG, const u16* __restrict__ XS,
    const u16* __restrict__ a1, const u16* __restrict__ a2,
    void* __restrict__ OUT, const int* __restrict__ dflag, int n){
  int wid = (blockIdx.x * 256 + threadIdx.x) >> 6;
  int lane = threadIdx.x & 63;
  if (wid >= n) return;
  int isbf = dflag[0];
  int c0 = lane * 4;
  size_t base = (size_t)wid * 256 + c0;
  float g[4], s[4];
#pragma unroll
  for (int e = 0; e < 4; e++){ g[e] = b2f(XG[base + e]); s[e] = b2f(XS[base + e]); }
  float p1 = 0.f, p2 = 0.f;
#pragma unroll
  for (int e = 0; e < 4; e++){
    p1 += g[e] * b2f(a1[c0 + e]) + s[e] * b2f(a1[256 + c0 + e]);
    p2 += g[e] * b2f(a2[c0 + e]) + s[e] * b2f(a2[256 + c0 + e]);
  }
#pragma unroll
  for (int d = 32; d > 0; d >>= 1){
    p1 += __shfl_xor(p1, d, 64);
    p2 += __shfl_xor(p2, d, 64);
  }
  float e1 = (p1 > 0.f) ? p1 : 0.2f * p1;
  float e2 = (p2 > 0.f) ? p2 : 0.2f * p2;
  float mx = fmaxf(e1, e2);
  float w1 = __expf(e1 - mx), w2 = __expf(e2 - mx);
  float inv = 1.f / (w1 + w2);
  float l0 = w1 * inv, l1 = w2 * inv;
#pragma unroll
  for (int e = 0; e < 4; e++)
    stout(OUT, (size_t)OFF_RES + base + e, l0 * g[e] + l1 * s[e], isbf);
  if (lane == 0){
    stout(OUT, (size_t)OFF_LAM + (size_t)wid * 2,     l0, isbf);
    stout(OUT, (size_t)OFF_LAM + (size_t)wid * 2 + 1, l1, isbf);
  }
}

extern "C" void kernel_launch(void* const* d_in, const int* in_sizes, int n_in,
                              void* d_out, int out_size, void* d_ws, size_t ws_size,
                              hipStream_t stream) {
  const void* gene_freq = d_in[0];
  const void* gene_eig  = d_in[1];
  const void* spot_freq = d_in[2];
  const void* spot_eig  = d_in[3];
  const int* net1 = (const int*)d_in[4];
  const int* net2 = (const int*)d_in[5];
  const void *c1_Wl=d_in[6],  *c1_bl=d_in[7],  *c1_Wr=d_in[8],  *c1_br=d_in[9],  *c1_att=d_in[10], *c1_b=d_in[11];
  const void *c1p_Wl=d_in[12],*c1p_bl=d_in[13],*c1p_Wr=d_in[14],*c1p_br=d_in[15],*c1p_att=d_in[16],*c1p_b=d_in[17];
  const void *c3_Wl=d_in[18], *c3_bl=d_in[19], *c3_Wr=d_in[20], *c3_br=d_in[21], *c3_att=d_in[22], *c3_b=d_in[23];
  const void *c3p_Wl=d_in[24],*c3p_bl=d_in[25],*c3p_Wr=d_in[26],*c3p_br=d_in[27],*c3p_att=d_in[28],*c3p_b=d_in[29];
  const void *W2=d_in[30], *b2=d_in[31], *W4=d_in[32], *b4=d_in[33], *a1=d_in[34], *a2=d_in[35];

  // ---- workspace carve: common area then region R ----
  char* p0 = (char*)d_ws;
  char* p = p0;
  auto carve = [&](size_t bytes) -> char* {
    char* r = p; p += (bytes + 255) & ~(size_t)255; return r;
  };
  int*   flag  = (int*) carve(256);
  int*   cnt1  = (int*) carve((NSPOT + 2) * 4);
  int*   off1  = (int*) carve((NSPOT + 2) * 4);
  int*   cur1  = (int*) carve((NSPOT + 2) * 4);
  int*   srcs1 = (int*) carve((size_t)E1N * 4);
  int*   cnt2  = (int*) carve((NSPOT + 2) * 4);
  int*   off2  = (int*) carve((NSPOT + 2) * 4);
  int*   cur2  = (int*) carve((NSPOT + 2) * 4);
  int*   srcs2 = (int*) carve((size_t)E2N * 4);
  u16*   Wcat1 = (u16*) carve(256 * 768 * 2);
  u16*   bcat1 = (u16*) carve(2048);
  u16*   Wcat2 = (u16*) carve(16 * 768 * 2);
  u16*   bcat2 = (u16*) carve(2048);
  u16*   attc1  = (u16*)carve(192 * 2);
  u16*   attc1p = (u16*)carve(192 * 2);
  u16*   attc3  = (u16*)carve(192 * 2);
  u16*   attc3p = (u16*)carve(192 * 2);
  u16*   bc1  = (u16*)carve(64 * 2);
  u16*   bc1p = (u16*)carve(64 * 2);
  u16*   bc3  = (u16*)carve(64 * 2);
  u16*   bc3p = (u16*)carve(64 * 2);
  u16*   W2c  = (u16*)carve(2048 * 2);
  u16*   b2c  = (u16*)carve(16 * 2);
  u16*   W4c  = (u16*)carve(32768 * 2);
  u16*   b4c  = (u16*)carve(256 * 2);
  u16*   a1c  = (u16*)carve(512 * 2);
  u16*   a2c  = (u16*)carve(512 * 2);
  u16*   GF16 = (u16*) carve((size_t)256 * 3000 * 2);
  u16*   SE16 = (u16*) carve((size_t)256 * 256 * 2);
  float* H2   = (float*)carve((size_t)NSPOT * 16 * 4);
  u16*   AGG  = (u16*)  carve((size_t)NSPOT * 128 * 2);
  u16*   XGp  = (u16*)  carve((size_t)NSPOT * 256 * 2);   // persistent XG (plan A)
  char*  R    = carve(0);                                  // region start
  size_t used_common = (size_t)(R - p0);
  size_t needA = used_common + (size_t)NSPOT * NGENE * 2 + 4096;
  bool planA = (ws_size >= needA);

  // --- common prologue ---
  sniff_kernel<<<1, 64, 0, stream>>>((const u16*)spot_freq, flag);
  hipMemsetAsync(cnt1, 0, NSPOT * 4, stream);
  hipMemsetAsync(cnt2, 0, NSPOT * 4, stream);
  hist_kernel<<<(E1N + 255) / 256, 256, 0, stream>>>(net1 + E1N, cnt1, E1N);
  hist_kernel<<<(E2N + 255) / 256, 256, 0, stream>>>(net2 + E2N, cnt2, E2N);
  scan_kernel<<<1, 256, 0, stream>>>(cnt1, off1, cur1, NSPOT);
  scan_kernel<<<1, 256, 0, stream>>>(cnt2, off2, cur2, NSPOT);
  scatter_kernel<<<(E1N + 255) / 256, 256, 0, stream>>>(net1, net1 + E1N, cur1, srcs1, E1N);
  scatter_kernel<<<(E2N + 255) / 256, 256, 0, stream>>>(net2, net2 + E2N, cur2, srcs2, E2N);

  ConvBatch cb;
  cb.s[0]  = {c1_att,  attc1,  192}; cb.s[1]  = {c1p_att, attc1p, 192};
  cb.s[2]  = {c3_att,  attc3,  192}; cb.s[3]  = {c3p_att, attc3p, 192};
  cb.s[4]  = {c1_b, bc1, 64}; cb.s[5]  = {c1p_b, bc1p, 64};
  cb.s[6]  = {c3_b, bc3, 64}; cb.s[7]  = {c3p_b, bc3p, 64};
  cb.s[8]  = {W2, W2c, 2048}; cb.s[9]  = {b2, b2c, 16};
  cb.s[10] = {W4, W4c, 32768}; cb.s[11] = {b4, b4c, 256};
  cb.s[12] = {a1, a1c, 512}; cb.s[13] = {a2, a2c, 512};
  convbatch_kernel<<<dim3(128, 14), 256, 0, stream>>>(cb, flag);
  conv4_kernel<<<(256 * 3000 / 4 + 255) / 256, 256, 0, stream>>>(gene_freq, GF16, 256 * 3000 / 4, flag);
  conv4_kernel<<<(256 * 256 / 4 + 255) / 256, 256, 0, stream>>>(spot_eig, SE16, 256 * 256 / 4, flag);

  assemble_kernel<<<(256 * 768 + 255) / 256, 256, 0, stream>>>(
      c1_Wl, c1_bl, c1_Wr, c1_br, c1p_Wl, c1p_bl, c1p_Wr, c1p_br, Wcat1, bcat1, 256, flag);
  assemble_kernel<<<(16 * 768 + 255) / 256, 256, 0, stream>>>(
      c3_Wl, c3_bl, c3_Wr, c3_br, c3p_Wl, c3p_bl, c3p_Wr, c3p_br, Wcat2, bcat2, 16, flag);

  if (planA){
    u16* AT   = (u16*)R;                              // [20000][3000], dead after Xg
    u16* SF16 = (u16*)R;                              // reuse R after Xg
    u16* Y    = (u16*)(R + 10485760);                 // [20000][768]
    u16* XS   = (u16*)(R + 10485760 + 31457280);      // [20000][256]
    u16* XG   = XGp;

    // transpose gene_eig [3000][20000] -> AT [20000][3000] bf16
    transpose_kernel<<<dim3(313, 47), 256, 0, stream>>>(gene_eig, AT, flag, NGENE, NSPOT);
    // Xg = relu(AT @ GF16^T)  M=20000 N=256 K=3000
    gemm_mfma<1, false, true, false, false, true, false, false><<<dim3(4, 313), 256, 0, stream>>>(
        AT, GF16, nullptr, XG, flag, 0, 0, NSPOT, 256, NGENE, NGENE, NGENE, 256);
    // spot_freq -> bf16 (into R, AT now dead)
    conv4_kernel<<<(NSPOT * 256 / 4 + 255) / 256, 256, 0, stream>>>(spot_freq, SF16, NSPOT * 256 / 4, flag);
    // Y = SF16 @ Wcat1 + bcat1  M=20000 N=768 K=256
    gemm_mfma<2, false, false, false, false, false, true, false><<<dim3(12, 157), 256, 0, stream>>>(
        SF16, Wcat1, bcat1, Y, flag, 0, 0, NSPOT, 768, 256, 256, 768, 768);
    // layer 1 GAT
    gat_kernel<<<5000, 256, 0, stream>>>(Y, 0,   192, off1, srcs1, attc1,  bc1,  AGG, 0,  NSPOT, E1N);
    gat_kernel<<<5000, 256, 0, stream>>>(Y, 384, 576, off2, srcs2, attc1p, bc1p, AGG, 64, NSPOT, E2N);
    h2_kernel<<<1250, 256, 0, stream>>>(AGG, W2c, b2c, H2, d_out, flag, NSPOT);
    y2_kernel<<<1250, 256, 0, stream>>>(H2, Wcat2, bcat2, Y, NSPOT);
    gat_kernel<<<5000, 256, 0, stream>>>(Y, 0,   192, off1, srcs1, attc3,  bc3,  AGG, 0,  NSPOT, E1N);
    gat_kernel<<<5000, 256, 0, stream>>>(Y, 384, 576, off2, srcs2, attc3p, bc3p, AGG, 64, NSPOT, E2N);
    // h4 -> d_out
    gemm_mfma<1, false, false, false, false, false, true, true><<<dim3(4, 313), 256, 0, stream>>>(
        AGG, W4c, b4c, d_out, flag, 0, OFF_H4, NSPOT, 256, 128, 128, 256, 256);
    // Xs = relu(h4 @ SE16)
    gemm_mfma<1, false, false, true, false, true, false, false><<<dim3(4, 313), 256, 0, stream>>>(
        d_out, SE16, nullptr, XS, flag, OFF_H4, 0, NSPOT, 256, 256, 256, 256, 256);
    cross_attn_kernel<<<5000, 256, 0, stream>>>(XG, XS, a1c, a2c, d_out, flag, NSPOT);
  } else {
    // fallback: round-2 proven path (small ws)
    u16* Y  = (u16*)R;
    u16* XG = Y;
    u16* XS = Y + 5120000;
    gemm_mfma<2, false, false, true, false, false, true, false><<<dim3(12, 157), 256, 0, stream>>>(
        spot_freq, Wcat1, bcat1, Y, flag, 0, 0, NSPOT, 768, 256, 256, 768, 768);
    gat_kernel<<<5000, 256, 0, stream>>>(Y, 0,   192, off1, srcs1, attc1,  bc1,  AGG, 0,  NSPOT, E1N);
    gat_kernel<<<5000, 256, 0, stream>>>(Y, 384, 576, off2, srcs2, attc1p, bc1p, AGG, 64, NSPOT, E2N);
    h2_kernel<<<1250, 256, 0, stream>>>(AGG, W2c, b2c, H2, d_out, flag, NSPOT);
    y2_kernel<<<1250, 256, 0, stream>>>(H2, Wcat2, bcat2, Y, NSPOT);
    gat_kernel<<<5000, 256, 0, stream>>>(Y, 0,   192, off1, srcs1, attc3,  bc3,  AGG, 0,  NSPOT, E1N);
    gat_kernel<<<5000, 256, 0, stream>>>(Y, 384, 576, off2, srcs2, attc3p, bc3p, AGG, 64, NSPOT, E2N);
    gemm_mfma<2, false, false, false, false, false, true, true><<<dim3(4, 157), 256, 0, stream>>>(
        AGG, W4c, b4c, d_out, flag, 0, OFF_H4, NSPOT, 256, 128, 128, 256, 256);
    gemm_mfma<2, false, false, true, true, true, false, false><<<dim3(4, 157), 256, 0, stream>>>(
        d_out, spot_eig, nullptr, XS, flag, OFF_H4, 0, NSPOT, 256, 256, 256, 256, 256);
    gemm_mfma<2, true, true, true, true, true, false, false><<<dim3(4, 157), 256, 0, stream>>>(
        gene_eig, gene_freq, nullptr, XG, flag, 0, 0, NSPOT, 256, NGENE, NSPOT, NGENE, 256);
    cross_attn_kernel<<<5000, 256, 0, stream>>>(XG, XS, a1c, a2c, d_out, flag, NSPOT);
  }

  (void)in_sizes; (void)n_in; (void)out_size; (void)ws_size;
}

// Round 3
// 1091.457 us; speedup vs baseline: 1.2547x; 1.0279x over previous
//
#include <hip/hip_runtime.h>

typedef unsigned short u16;
typedef __attribute__((ext_vector_type(8))) short bf16x8;   // 8 x bf16 bits
typedef __attribute__((ext_vector_type(4))) float floatx4;

#define NSPOT 20000
#define NGENE 3000
#define E1N   640000
#define E2N   320000

// output element offsets (res, lam, h2, h4 concatenated)
#define OFF_RES 0
#define OFF_LAM 5120000
#define OFF_H2  5160000
#define OFF_H4  5480000

__device__ __forceinline__ float b2f(u16 u){
  union { unsigned int i; float f; } v; v.i = ((unsigned int)u) << 16; return v.f;
}
__device__ __forceinline__ u16 f2b(float f){
  union { float f; unsigned int i; } v; v.f = f;
  unsigned int i = v.i;
  return (u16)((i + 0x7FFFu + ((i >> 16) & 1u)) >> 16);
}
__device__ __forceinline__ void stout(void* O, size_t i, float v, int isbf){
  if (isbf) ((u16*)O)[i] = f2b(v); else ((float*)O)[i] = v;
}
__device__ __forceinline__ u16 ldu(const void* p, size_t i, int isbf){
  return isbf ? ((const u16*)p)[i] : f2b(((const float*)p)[i]);
}

// ---------------- dtype sniffer ----------------
__global__ void sniff_kernel(const u16* __restrict__ x, int* __restrict__ flag){
  int lane = threadIdx.x;
  u16 u = x[lane * 2];
  int e = (u >> 7) & 0xFF;
  int sane = (u == 0) || (e >= 0x60 && e <= 0xA0);
  unsigned long long b = __ballot(sane);
  if (lane == 0) flag[0] = (__popcll(b) >= 48) ? 1 : 0;
}

// ---------------- batched small-param convert ----------------
struct ConvSeg { const void* src; u16* dst; int n; };
struct ConvBatch { ConvSeg s[14]; };
__global__ void convbatch_kernel(ConvBatch cb, const int* __restrict__ dflag){
  ConvSeg S = cb.s[blockIdx.y];
  int i = blockIdx.x * 256 + threadIdx.x;
  if (i < S.n) S.dst[i] = ldu(S.src, i, dflag[0]);
}

// fused vectorized convert of the 3 big tensors (each n multiple of 4)
__global__ void conv3_kernel(const void* __restrict__ s0, u16* __restrict__ d0, int n0,
                             const void* __restrict__ s1, u16* __restrict__ d1, int n1,
                             const void* __restrict__ s2, u16* __restrict__ d2, int n2,
                             const int* __restrict__ dflag){
  int i = blockIdx.x * 256 + threadIdx.x;
  const void* src; u16* dst; int local;
  if (i < n0){ src = s0; dst = d0; local = i; }
  else if (i < n0 + n1){ src = s1; dst = d1; local = i - n0; }
  else if (i < n0 + n1 + n2){ src = s2; dst = d2; local = i - n0 - n1; }
  else return;
  size_t b = (size_t)local * 4;
  u16 o[4];
  if (dflag[0]){
    *(uint2*)o = *(const uint2*)((const u16*)src + b);
  } else {
    float4 f = *(const float4*)((const float*)src + b);
    o[0]=f2b(f.x); o[1]=f2b(f.y); o[2]=f2b(f.z); o[3]=f2b(f.w);
  }
  *(uint2*)(dst + b) = *(uint2*)o;
}

// ---------------- transpose GE[K][M] -> AT[M][K] bf16 ----
__global__ __launch_bounds__(256) void transpose_kernel(
    const void* __restrict__ GE, u16* __restrict__ AT,
    const int* __restrict__ dflag, int K, int M){
  __shared__ float tile[64 * 65];
  int isbf = dflag[0];
  int m0 = blockIdx.x * 64, k0 = blockIdx.y * 64;
#pragma unroll
  for (int i = 0; i < 4; i++){
    int idx = threadIdx.x + i * 256;
    int kr = idx >> 4, mc = (idx & 15) * 4;
    int gk = k0 + kr, gm = m0 + mc;
    if (gk < K){
      float v0 = 0.f, v1 = 0.f, v2 = 0.f, v3 = 0.f;
      if (gm + 4 <= M){
        if (isbf){
          const u16* pp = (const u16*)GE + (size_t)gk * M + gm;
          v0 = b2f(pp[0]); v1 = b2f(pp[1]); v2 = b2f(pp[2]); v3 = b2f(pp[3]);
        } else {
          float4 f = *(const float4*)((const float*)GE + (size_t)gk * M + gm);
          v0 = f.x; v1 = f.y; v2 = f.z; v3 = f.w;
        }
      } else {
        for (int e = 0; e < 4; e++){
          if (gm + e < M){
            float t = isbf ? b2f(((const u16*)GE)[(size_t)gk * M + gm + e])
                           : ((const float*)GE)[(size_t)gk * M + gm + e];
            if (e == 0) v0 = t; else if (e == 1) v1 = t; else if (e == 2) v2 = t; else v3 = t;
          }
        }
      }
      tile[(mc + 0) * 65 + kr] = v0;
      tile[(mc + 1) * 65 + kr] = v1;
      tile[(mc + 2) * 65 + kr] = v2;
      tile[(mc + 3) * 65 + kr] = v3;
    }
  }
  __syncthreads();
#pragma unroll
  for (int i = 0; i < 2; i++){
    int idx = threadIdx.x + i * 256;
    int mr = idx >> 3, kc = (idx & 7) * 8;
    int gm = m0 + mr, gk = k0 + kc;
    if (gm < M && gk < K){
      if (gk + 8 <= K){
        u16 o[8];
#pragma unroll
        for (int e = 0; e < 8; e++) o[e] = f2b(tile[mr * 65 + kc + e]);
        *(uint4*)&AT[(size_t)gm * K + gk] = *(uint4*)o;
      } else {
        for (int e = 0; e < 8 && gk + e < K; e++)
          AT[(size_t)gm * K + gk + e] = f2b(tile[mr * 65 + kc + e]);
      }
    }
  }
}

// ---------------- CSR build (fused E1+E2 via grid.y / blockIdx.x) ----------------
__global__ void hist2_kernel(const int* __restrict__ dst0, int E0, int* __restrict__ cnt0,
                             const int* __restrict__ dst1, int E1, int* __restrict__ cnt1){
  const int* dst = blockIdx.y ? dst1 : dst0;
  int* cnt = blockIdx.y ? cnt1 : cnt0;
  int E = blockIdx.y ? E1 : E0;
  int e = blockIdx.x * 256 + threadIdx.x;
  if (e < E){ int d = dst[e]; if ((unsigned)d < (unsigned)NSPOT) atomicAdd(&cnt[d], 1); }
}

__global__ void scan2_kernel(const int* __restrict__ c0, int* __restrict__ o0, int* __restrict__ u0,
                             const int* __restrict__ c1, int* __restrict__ o1, int* __restrict__ u1,
                             int n){
  const int* cnt = blockIdx.x ? c1 : c0;
  int* off = blockIdx.x ? o1 : o0;
  int* cur = blockIdx.x ? u1 : u0;
  __shared__ int part[256];
  int tid = threadIdx.x;
  int chunk = (n + 255) / 256;
  int lo = tid * chunk; if (lo > n) lo = n;
  int hi = lo + chunk; if (hi > n) hi = n;
  int s = 0;
  for (int i = lo; i < hi; i++) s += cnt[i];
  part[tid] = s;
  __syncthreads();
  if (tid == 0){
    int run = 0;
    for (int i = 0; i < 256; i++){ int t = part[i]; part[i] = run; run += t; }
  }
  __syncthreads();
  int run = part[tid];
  for (int i = lo; i < hi; i++){ off[i] = run; cur[i] = run; run += cnt[i]; }
  if (hi == n) off[n] = run;
}

__global__ void scatter2_kernel(const int* __restrict__ src0, const int* __restrict__ dst0,
                                int* __restrict__ cur0, int* __restrict__ out0, int E0,
                                const int* __restrict__ src1, const int* __restrict__ dst1,
                                int* __restrict__ cur1, int* __restrict__ out1, int E1){
  const int* src = blockIdx.y ? src1 : src0;
  const int* dst = blockIdx.y ? dst1 : dst0;
  int* cur = blockIdx.y ? cur1 : cur0;
  int* out = blockIdx.y ? out1 : out0;
  int E = blockIdx.y ? E1 : E0;
  int e = blockIdx.x * 256 + threadIdx.x;
  if (e < E){
    int d = dst[e];
    if ((unsigned)d < (unsigned)NSPOT){
      int p = atomicAdd(&cur[d], 1);
      if ((unsigned)p < (unsigned)E) out[p] = src[e];
    }
  }
}

// ---------------- weight concat (both layers in one launch) ----------------
struct AsmSet {
  const void *Wl, *bl, *Wr, *br, *Wlp, *blp, *Wrp, *brp;
  u16* Wcat; u16* bcat; int Kdim;
};
__global__ void assemble2_kernel(AsmSet s0, AsmSet s1, const int* __restrict__ dflag){
  AsmSet S = blockIdx.y ? s1 : s0;
  int isbf = dflag[0];
  int idx = blockIdx.x * 256 + threadIdx.x;
  int total = S.Kdim * 768;
  if (idx < total){
    int k = idx / 768, j = idx % 768;
    int seg = j / 192, jj = j % 192;
    const void* W = (seg == 0) ? S.Wl : (seg == 1) ? S.Wr : (seg == 2) ? S.Wlp : S.Wrp;
    S.Wcat[idx] = ldu(W, (size_t)k * 192 + jj, isbf);
  }
  if (idx < 768){
    int seg = idx / 192, jj = idx % 192;
    const void* b = (seg == 0) ? S.bl : (seg == 1) ? S.br : (seg == 2) ? S.blp : S.brp;
    S.bcat[idx] = ldu(b, jj, isbf);
  }
}

// ---------------- MFMA GEMM (BM = 64*BMI, BN=64) ----------------
template<int BMI, bool A_KM, bool B_NK, bool A_EXT, bool B_EXT, bool RELU, bool HAS_BIAS, bool C_OUT, bool C2>
__global__ __launch_bounds__(256) void gemm_mfma(
    const void* __restrict__ A, const void* __restrict__ B,
    const u16* __restrict__ bias, void* __restrict__ Cp, u16* __restrict__ Cp2,
    const int* __restrict__ dflag, size_t aoff, size_t coff,
    int M, int N, int K, int lda, int ldb, int ldc, int ldc2)
{
  const int isbf = dflag[0];
  constexpr int BM = 64 * BMI, BK = 32, LDA = BK + 8, LDB = BK + 8;
  __shared__ __align__(16) u16 As[BM * LDA];
  __shared__ __align__(16) u16 Bs[64 * LDB];
  const u16*   A16 = (const u16*)A + aoff;
  const float* A32 = (const float*)A + aoff;
  const u16*   B16 = (const u16*)B;
  const float* B32 = (const float*)B;
  auto ldA = [&](size_t i) -> u16 { return (!A_EXT || isbf) ? A16[i] : f2b(A32[i]); };
  auto ldB = [&](size_t i) -> u16 { return (!B_EXT || isbf) ? B16[i] : f2b(B32[i]); };

  int tid = threadIdx.x;
  int lane = tid & 63, w = tid >> 6;
  int m0 = blockIdx.y * BM, n0 = blockIdx.x * 64;
  floatx4 acc[BMI][4] = {};
  int quad = lane >> 4;
  int nk = (K + BK - 1) / BK;
  for (int kt = 0; kt < nk; kt++){
    int k0 = kt * BK;
    // ---- stage A -> As[m][k] ----
    if (!A_KM){
#pragma unroll
      for (int i = 0; i < BMI; i++){
        int id = tid + i * 256;
        int r = id >> 2, c = (id & 3) * 8;
        int gm = m0 + r, gk = k0 + c;
        if (gm < M && gk + 8 <= K){
          if (!A_EXT || isbf){
            *(uint4*)&As[r * LDA + c] = *(const uint4*)(A16 + (size_t)gm * lda + gk);
          } else {
            const float* p = A32 + (size_t)gm * lda + gk;
            float4 f0 = *(const float4*)p, f1 = *(const float4*)(p + 4);
            u16* d = &As[r * LDA + c];
            d[0]=f2b(f0.x); d[1]=f2b(f0.y); d[2]=f2b(f0.z); d[3]=f2b(f0.w);
            d[4]=f2b(f1.x); d[5]=f2b(f1.y); d[6]=f2b(f1.z); d[7]=f2b(f1.w);
          }
        } else {
          for (int e = 0; e < 8; e++)
            As[r * LDA + c + e] = (gm < M && gk + e < K) ? ldA((size_t)gm * lda + gk + e) : (u16)0;
        }
      }
    } else {
#pragma unroll
      for (int i = 0; i < BMI; i++){
        int id = tid + i * 256;
        int kk, rr;
        if (BMI == 2){ kk = id >> 4; rr = (id & 15) * 8; }
        else         { kk = id >> 3; rr = (id & 7) * 8; }
        int gk = k0 + kk, gm = m0 + rr;
        if (gk < K && gm + 8 <= M){
          if (!A_EXT || isbf){
            uint4 v = *(const uint4*)(A16 + (size_t)gk * lda + gm);
            const u16* pv = (const u16*)&v;
#pragma unroll
            for (int e = 0; e < 8; e++) As[(rr + e) * LDA + kk] = pv[e];
          } else {
            const float* p = A32 + (size_t)gk * lda + gm;
            float4 f0 = *(const float4*)p, f1 = *(const float4*)(p + 4);
            As[(rr+0)*LDA+kk]=f2b(f0.x); As[(rr+1)*LDA+kk]=f2b(f0.y);
            As[(rr+2)*LDA+kk]=f2b(f0.z); As[(rr+3)*LDA+kk]=f2b(f0.w);
            As[(rr+4)*LDA+kk]=f2b(f1.x); As[(rr+5)*LDA+kk]=f2b(f1.y);
            As[(rr+6)*LDA+kk]=f2b(f1.z); As[(rr+7)*LDA+kk]=f2b(f1.w);
          }
        } else {
          for (int e = 0; e < 8; e++)
            As[(rr + e) * LDA + kk] = (gk < K && gm + e < M) ? ldA((size_t)gk * lda + gm + e) : (u16)0;
        }
      }
    }
    // ---- stage B -> Bs[n][k] ----
    if (B_NK){
      int r = tid >> 2, c = (tid & 3) * 8;
      int gn = n0 + r, gk = k0 + c;
      if (gn < N && gk + 8 <= K){
        if (!B_EXT || isbf){
          *(uint4*)&Bs[r * LDB + c] = *(const uint4*)(B16 + (size_t)gn * ldb + gk);
        } else {
          const float* p = B32 + (size_t)gn * ldb + gk;
          float4 f0 = *(const float4*)p, f1 = *(const float4*)(p + 4);
          u16* d = &Bs[r * LDB + c];
          d[0]=f2b(f0.x); d[1]=f2b(f0.y); d[2]=f2b(f0.z); d[3]=f2b(f0.w);
          d[4]=f2b(f1.x); d[5]=f2b(f1.y); d[6]=f2b(f1.z); d[7]=f2b(f1.w);
        }
      } else {
        for (int e = 0; e < 8; e++)
          Bs[r * LDB + c + e] = (gn < N && gk + e < K) ? ldB((size_t)gn * ldb + gk + e) : (u16)0;
      }
    } else {
      int kk = tid >> 3, nn = (tid & 7) * 8;
      int gk = k0 + kk, gn = n0 + nn;
      if (gk < K && gn + 8 <= N){
        if (!B_EXT || isbf){
          uint4 v = *(const uint4*)(B16 + (size_t)gk * ldb + gn);
          const u16* pv = (const u16*)&v;
#pragma unroll
          for (int e = 0; e < 8; e++) Bs[(nn + e) * LDB + kk] = pv[e];
        } else {
          const float* p = B32 + (size_t)gk * ldb + gn;
          float4 f0 = *(const float4*)p, f1 = *(const float4*)(p + 4);
          Bs[(nn+0)*LDB+kk]=f2b(f0.x); Bs[(nn+1)*LDB+kk]=f2b(f0.y);
          Bs[(nn+2)*LDB+kk]=f2b(f0.z); Bs[(nn+3)*LDB+kk]=f2b(f0.w);
          Bs[(nn+4)*LDB+kk]=f2b(f1.x); Bs[(nn+5)*LDB+kk]=f2b(f1.y);
          Bs[(nn+6)*LDB+kk]=f2b(f1.z); Bs[(nn+7)*LDB+kk]=f2b(f1.w);
        }
      } else {
        for (int e = 0; e < 8; e++)
          Bs[(nn + e) * LDB + kk] = (gk < K && gn + e < N) ? ldB((size_t)gk * ldb + gn + e) : (u16)0;
      }
    }
    __syncthreads();
    // ---- MFMA ----
    bf16x8 af[BMI];
#pragma unroll
    for (int mi = 0; mi < BMI; mi++)
      af[mi] = *(const bf16x8*)&As[(w * (16 * BMI) + mi * 16 + (lane & 15)) * LDA + quad * 8];
#pragma unroll
    for (int ni = 0; ni < 4; ni++){
      bf16x8 bfr = *(const bf16x8*)&Bs[(ni * 16 + (lane & 15)) * LDB + quad * 8];
#pragma unroll
      for (int mi = 0; mi < BMI; mi++)
        acc[mi][ni] = __builtin_amdgcn_mfma_f32_16x16x32_bf16(af[mi], bfr, acc[mi][ni], 0, 0, 0);
    }
    __syncthreads();
  }
  // ---- epilogue ----
#pragma unroll
  for (int mi = 0; mi < BMI; mi++)
#pragma unroll
    for (int ni = 0; ni < 4; ni++)
#pragma unroll
      for (int r = 0; r < 4; r++){
        int row = m0 + w * (16 * BMI) + mi * 16 + quad * 4 + r;
        int col = n0 + ni * 16 + (lane & 15);
        if (row < M && col < N){
          float v = acc[mi][ni][r];
          if (HAS_BIAS) v += b2f(bias[col]);
          if (RELU) v = fmaxf(v, 0.f);
          size_t ci = coff + (size_t)row * ldc + col;
          if (!C_OUT) ((u16*)Cp)[ci] = f2b(v);
          else stout(Cp, ci, v, isbf);
          if (C2) Cp2[(size_t)row * ldc2 + col] = f2b(v);
        }
      }
}

// ---------------- GATv2 aggregation: both edge sets in one launch ----------------
// blocks [0, half) -> set A (E1), [half, 2*half) -> set B (E2).
// 4 edges per iteration, 16 lanes per edge (lane = sub*16 + c16, each lane
// owns 4 consecutive channels per head).
struct GatSet {
  const int* off; const int* srcs; const u16* att; const u16* bias;
  int xl_off, xr_off, out_off, E;
};
__global__ __launch_bounds__(256) void gat2_kernel(
    const u16* __restrict__ Y, GatSet SA, GatSet SB,
    u16* __restrict__ aggout, int n)
{
  int half = gridDim.x >> 1;
  int selB = (int)blockIdx.x >= half;
  GatSet S = selB ? SB : SA;
  int bx = blockIdx.x - (selB ? half : 0);
  int wid = (bx * 256 + threadIdx.x) >> 6;
  int lane = threadIdx.x & 63;
  if (wid >= n) return;
  int sub = lane >> 4;          // edge slot within chunk (0..3)
  int cbase = (lane & 15) * 4;  // 4 consecutive channels per head
  const int ldY = 768;
  size_t drow = (size_t)wid * ldY;

  // xr (dst transform) and att, loaded once per dst: 3 heads x 4 channels each
  float xr[3][4], at[3][4];
#pragma unroll
  for (int h = 0; h < 3; h++){
    uint2 vx = *(const uint2*)(Y + drow + S.xr_off + h * 64 + cbase);
    uint2 va = *(const uint2*)(S.att + h * 64 + cbase);
    const u16* px = (const u16*)&vx;
    const u16* pa = (const u16*)&va;
#pragma unroll
    for (int j = 0; j < 4; j++){ xr[h][j] = b2f(px[j]); at[h][j] = b2f(pa[j]); }
  }

  int beg = S.off[wid], end = S.off[wid + 1];
  beg = max(0, min(beg, S.E));
  end = max(beg, min(end, S.E));

  float mh[3] = {-INFINITY, -INFINITY, -INFINITY};
  float lh[3] = {0.f, 0.f, 0.f};
  float ac[3][4] = {};

  // prefetch: gather for chunk 0, src index for chunk 1
  uint2 xa[3] = {};
  int s_b = 0;
  if (beg < end){
    int e0 = beg + sub;
    int s = (e0 < end) ? S.srcs[e0] : 0;
    if ((unsigned)s >= (unsigned)NSPOT) s = 0;
    const u16* p = Y + (size_t)s * ldY + S.xl_off + cbase;
#pragma unroll
    for (int h = 0; h < 3; h++) xa[h] = *(const uint2*)(p + h * 64);
    if (beg + 4 < end){
      int e1 = beg + 4 + sub;
      int s1 = (e1 < end) ? S.srcs[e1] : 0;
      if ((unsigned)s1 >= (unsigned)NSPOT) s1 = 0;
      s_b = s1;
    }
  }

  for (int b = beg; b < end; b += 4){
    uint2 xc[3];
#pragma unroll
    for (int h = 0; h < 3; h++) xc[h] = xa[h];
    bool act = (b + sub) < end;

    // issue gather for chunk b+4 (index already resident), fetch index for b+8
    if (b + 4 < end){
      const u16* p = Y + (size_t)s_b * ldY + S.xl_off + cbase;
#pragma unroll
      for (int h = 0; h < 3; h++) xa[h] = *(const uint2*)(p + h * 64);
      if (b + 8 < end){
        int e2 = b + 8 + sub;
        int s2 = (e2 < end) ? S.srcs[e2] : 0;
        if ((unsigned)s2 >= (unsigned)NSPOT) s2 = 0;
        s_b = s2;
      }
    }

    // partial leaky-dot per lane (4 channels x 3 heads)
    float xl[3][4];
    float t0, t1, t2;
    {
      float a0 = 0.f, a1 = 0.f, a2 = 0.f;
      const u16* p0 = (const u16*)&xc[0];
      const u16* p1 = (const u16*)&xc[1];
      const u16* p2 = (const u16*)&xc[2];
#pragma unroll
      for (int j = 0; j < 4; j++){
        float x0 = b2f(p0[j]); xl[0][j] = x0;
        float u0 = x0 + xr[0][j]; u0 = fmaxf(u0, 0.2f * u0);
        a0 = __builtin_fmaf(at[0][j], u0, a0);
        float x1 = b2f(p1[j]); xl[1][j] = x1;
        float u1 = x1 + xr[1][j]; u1 = fmaxf(u1, 0.2f * u1);
        a1 = __builtin_fmaf(at[1][j], u1, a1);
        float x2 = b2f(p2[j]); xl[2][j] = x2;
        float u2 = x2 + xr[2][j]; u2 = fmaxf(u2, 0.2f * u2);
        a2 = __builtin_fmaf(at[2][j], u2, a2);
      }
      t0 = a0; t1 = a1; t2 = a2;
    }
    // reduce within each 16-lane subgroup (4 steps, 3 heads interleaved)
#pragma unroll
    for (int d = 1; d < 16; d <<= 1){
      t0 += __shfl_xor(t0, d, 64);
      t1 += __shfl_xor(t1, d, 64);
      t2 += __shfl_xor(t2, d, 64);
    }
    if (act){
      float tt[3] = {t0, t1, t2};
#pragma unroll
      for (int h = 0; h < 3; h++){
        float nm = fmaxf(mh[h], tt[h]);
        if (nm > mh[h]){
          float sc = __expf(mh[h] - nm);   // exp(-inf)=0 on first edge
          lh[h] *= sc;
#pragma unroll
          for (int j = 0; j < 4; j++) ac[h][j] *= sc;
          mh[h] = nm;
        }
        float w = __expf(tt[h] - mh[h]);
        lh[h] += w;
#pragma unroll
        for (int j = 0; j < 4; j++) ac[h][j] = __builtin_fmaf(w, xl[h][j], ac[h][j]);
      }
    }
  }

  // combine the 4 subgroups' online-softmax states (xor 16, 32 butterfly)
  float o[4] = {0.f, 0.f, 0.f, 0.f};
#pragma unroll
  for (int h = 0; h < 3; h++){
    float gm = fmaxf(mh[h], __shfl_xor(mh[h], 16, 64));
    gm = fmaxf(gm, __shfl_xor(gm, 32, 64));
    float sc = (mh[h] == -INFINITY) ? 0.f : __expf(mh[h] - gm);
    float L = lh[h] * sc;
    L += __shfl_xor(L, 16, 64);
    L += __shfl_xor(L, 32, 64);
    float inv = 1.f / fmaxf(L, 1e-16f);
#pragma unroll
    for (int j = 0; j < 4; j++){
      float a = ac[h][j] * sc;
      a += __shfl_xor(a, 16, 64);
      a += __shfl_xor(a, 32, 64);
      o[j] += a * inv;
    }
  }
  if (sub == 0){
    u16 ov[4];
#pragma unroll
    for (int j = 0; j < 4; j++){
      float v = o[j] * (1.f / 3.f) + b2f(S.bias[cbase + j]);
      v = (v > 0.f) ? v : expm1f(v);
      if (!(fabsf(v) < 1e30f)) v = 0.f;
      ov[j] = f2b(v);
    }
    *(uint2*)&aggout[(size_t)wid * 128 + S.out_off + cbase] = *(uint2*)ov;
  }
}

// ---------------- fused h2 = h1@W2+b2 ; Y2 = h2@Wcat2+bcat2 ----------------
__global__ __launch_bounds__(256) void h2y2_kernel(
    const u16* __restrict__ AGG, const u16* __restrict__ W2, const u16* __restrict__ b2,
    const u16* __restrict__ Wcat2, const u16* __restrict__ bcat2,
    void* __restrict__ OUT, u16* __restrict__ Y2,
    const int* __restrict__ dflag, int n){
  __shared__ float w2s[128 * 16];
  __shared__ float as_[16][128];
  __shared__ float h[16][16];
  __shared__ __align__(16) u16 ws_[16 * 768];
  int isbf = dflag[0];
  int tid = threadIdx.x;
  for (int i = tid; i < 128 * 16; i += 256) w2s[i] = b2f(W2[i]);
  for (int i = tid; i < 1536; i += 256) ((uint4*)ws_)[i] = ((const uint4*)Wcat2)[i];
  int m0 = blockIdx.x * 16;
  for (int i = tid; i < 16 * 128; i += 256){
    int r = i >> 7, c = i & 127; int m = m0 + r;
    as_[r][c] = (m < n) ? b2f(AGG[(size_t)m * 128 + c]) : 0.f;
  }
  __syncthreads();
  {
    int r = tid >> 4, j = tid & 15;
    int m = m0 + r;
    float acc = b2f(b2[j]);
    for (int k = 0; k < 128; k++) acc += as_[r][k] * w2s[k * 16 + j];
    h[r][j] = acc;
    if (m < n) stout(OUT, (size_t)OFF_H2 + (size_t)m * 16 + j, acc, isbf);
  }
  __syncthreads();
  // y2 phase: j = tid covers 256 of 768 cols, 3 segments
  int j = tid;
  float acc[16][3];
  float bj0 = b2f(bcat2[j]), bj1 = b2f(bcat2[j + 256]), bj2 = b2f(bcat2[j + 512]);
#pragma unroll
  for (int r = 0; r < 16; r++){ acc[r][0] = bj0; acc[r][1] = bj1; acc[r][2] = bj2; }
  for (int k = 0; k < 16; k++){
    float w0 = b2f(ws_[k * 768 + j]);
    float w1 = b2f(ws_[k * 768 + j + 256]);
    float w2 = b2f(ws_[k * 768 + j + 512]);
#pragma unroll
    for (int r = 0; r < 16; r++){
      float hv = h[r][k];
      acc[r][0] += hv * w0; acc[r][1] += hv * w1; acc[r][2] += hv * w2;
    }
  }
#pragma unroll
  for (int r = 0; r < 16; r++){
    int m = m0 + r;
    if (m < n){
      size_t base = (size_t)m * 768;
      Y2[base + j] = f2b(acc[r][0]);
      Y2[base + j + 256] = f2b(acc[r][1]);
      Y2[base + j + 512] = f2b(acc[r][2]);
    }
  }
}

// ---------------- Cross attention (wave per row) ----------------
__global__ __launch_bounds__(256) void cross_attn_kernel(
    const u16* __restrict__ XG, const u16* __restrict__ XS,
    const u16* __restrict__ a1, const u16* __restrict__ a2,
    void* __restrict__ OUT, const int* __restrict__ dflag, int n){
  int wid = (blockIdx.x * 256 + threadIdx.x) >> 6;
  int lane = threadIdx.x & 63;
  if (wid >= n) return;
  int isbf = dflag[0];
  int c0 = lane * 4;
  size_t base = (size_t)wid * 256 + c0;
  float g[4], s[4];
#pragma unroll
  for (int e = 0; e < 4; e++){ g[e] = b2f(XG[base + e]); s[e] = b2f(XS[base + e]); }
  float p1 = 0.f, p2 = 0.f;
#pragma unroll
  for (int e = 0; e < 4; e++){
    p1 += g[e] * b2f(a1[c0 + e]) + s[e] * b2f(a1[256 + c0 + e]);
    p2 += g[e] * b2f(a2[c0 + e]) + s[e] * b2f(a2[256 + c0 + e]);
  }
#pragma unroll
  for (int d = 32; d > 0; d >>= 1){
    p1 += __shfl_xor(p1, d, 64);
    p2 += __shfl_xor(p2, d, 64);
  }
  float e1 = (p1 > 0.f) ? p1 : 0.2f * p1;
  float e2 = (p2 > 0.f) ? p2 : 0.2f * p2;
  float mx = fmaxf(e1, e2);
  float w1 = __expf(e1 - mx), w2 = __expf(e2 - mx);
  float inv = 1.f / (w1 + w2);
  float l0 = w1 * inv, l1 = w2 * inv;
#pragma unroll
  for (int e = 0; e < 4; e++)
    stout(OUT, (size_t)OFF_RES + base + e, l0 * g[e] + l1 * s[e], isbf);
  if (lane == 0){
    stout(OUT, (size_t)OFF_LAM + (size_t)wid * 2,     l0, isbf);
    stout(OUT, (size_t)OFF_LAM + (size_t)wid * 2 + 1, l1, isbf);
  }
}

extern "C" void kernel_launch(void* const* d_in, const int* in_sizes, int n_in,
                              void* d_out, int out_size, void* d_ws, size_t ws_size,
                              hipStream_t stream) {
  const void* gene_freq = d_in[0];
  const void* gene_eig  = d_in[1];
  const void* spot_freq = d_in[2];
  const void* spot_eig  = d_in[3];
  const int* net1 = (const int*)d_in[4];
  const int* net2 = (const int*)d_in[5];
  const void *c1_Wl=d_in[6],  *c1_bl=d_in[7],  *c1_Wr=d_in[8],  *c1_br=d_in[9],  *c1_att=d_in[10], *c1_b=d_in[11];
  const void *c1p_Wl=d_in[12],*c1p_bl=d_in[13],*c1p_Wr=d_in[14],*c1p_br=d_in[15],*c1p_att=d_in[16],*c1p_b=d_in[17];
  const void *c3_Wl=d_in[18], *c3_bl=d_in[19], *c3_Wr=d_in[20], *c3_br=d_in[21], *c3_att=d_in[22], *c3_b=d_in[23];
  const void *c3p_Wl=d_in[24],*c3p_bl=d_in[25],*c3p_Wr=d_in[26],*c3p_br=d_in[27],*c3p_att=d_in[28],*c3p_b=d_in[29];
  const void *W2=d_in[30], *b2=d_in[31], *W4=d_in[32], *b4=d_in[33], *a1=d_in[34], *a2=d_in[35];

  // ---- workspace carve: common area then region R ----
  char* p0 = (char*)d_ws;
  char* p = p0;
  auto carve = [&](size_t bytes) -> char* {
    char* r = p; p += (bytes + 255) & ~(size_t)255; return r;
  };
  int*   flag  = (int*) carve(256);
  int*   cnt1  = (int*) carve((NSPOT + 2) * 4);
  int*   off1  = (int*) carve((NSPOT + 2) * 4);
  int*   cur1  = (int*) carve((NSPOT + 2) * 4);
  int*   srcs1 = (int*) carve((size_t)E1N * 4);
  int*   cnt2  = (int*) carve((NSPOT + 2) * 4);
  int*   off2  = (int*) carve((NSPOT + 2) * 4);
  int*   cur2  = (int*) carve((NSPOT + 2) * 4);
  int*   srcs2 = (int*) carve((size_t)E2N * 4);
  u16*   Wcat1 = (u16*) carve(256 * 768 * 2);
  u16*   bcat1 = (u16*) carve(2048);
  u16*   Wcat2 = (u16*) carve(16 * 768 * 2);
  u16*   bcat2 = (u16*) carve(2048);
  u16*   attc1  = (u16*)carve(192 * 2);
  u16*   attc1p = (u16*)carve(192 * 2);
  u16*   attc3  = (u16*)carve(192 * 2);
  u16*   attc3p = (u16*)carve(192 * 2);
  u16*   bc1  = (u16*)carve(64 * 2);
  u16*   bc1p = (u16*)carve(64 * 2);
  u16*   bc3  = (u16*)carve(64 * 2);
  u16*   bc3p = (u16*)carve(64 * 2);
  u16*   W2c  = (u16*)carve(2048 * 2);
  u16*   b2c  = (u16*)carve(16 * 2);
  u16*   W4c  = (u16*)carve(32768 * 2);
  u16*   b4c  = (u16*)carve(256 * 2);
  u16*   a1c  = (u16*)carve(512 * 2);
  u16*   a2c  = (u16*)carve(512 * 2);
  u16*   GF16 = (u16*) carve((size_t)256 * 3000 * 2);
  u16*   SE16 = (u16*) carve((size_t)256 * 256 * 2);
  u16*   SF16 = (u16*) carve((size_t)NSPOT * 256 * 2);   // spot_freq bf16
  u16*   H4B  = (u16*) carve((size_t)NSPOT * 256 * 2);   // bf16 copy of h4
  u16*   AGG  = (u16*) carve((size_t)NSPOT * 128 * 2);
  u16*   XGp  = (u16*) carve((size_t)NSPOT * 256 * 2);   // persistent XG
  char*  R    = carve(0);                                 // region start
  size_t used_common = (size_t)(R - p0);
  size_t needA = used_common + (size_t)NSPOT * NGENE * 2   // AT
               + (size_t)NSPOT * 768 * 2                   // Y
               + (size_t)NSPOT * 256 * 2                   // XS
               + 4096;
  bool planA = (ws_size >= needA);

  // --- common prologue ---
  sniff_kernel<<<1, 64, 0, stream>>>((const u16*)spot_freq, flag);
  hipMemsetAsync(cnt1, 0, NSPOT * 4, stream);
  hipMemsetAsync(cnt2, 0, NSPOT * 4, stream);
  hist2_kernel<<<dim3((E1N + 255) / 256, 2), 256, 0, stream>>>(
      net1 + E1N, E1N, cnt1, net2 + E2N, E2N, cnt2);
  scan2_kernel<<<2, 256, 0, stream>>>(cnt1, off1, cur1, cnt2, off2, cur2, NSPOT);
  scatter2_kernel<<<dim3((E1N + 255) / 256, 2), 256, 0, stream>>>(
      net1, net1 + E1N, cur1, srcs1, E1N, net2, net2 + E2N, cur2, srcs2, E2N);

  ConvBatch cb;
  cb.s[0]  = {c1_att,  attc1,  192}; cb.s[1]  = {c1p_att, attc1p, 192};
  cb.s[2]  = {c3_att,  attc3,  192}; cb.s[3]  = {c3p_att, attc3p, 192};
  cb.s[4]  = {c1_b, bc1, 64}; cb.s[5]  = {c1p_b, bc1p, 64};
  cb.s[6]  = {c3_b, bc3, 64}; cb.s[7]  = {c3p_b, bc3p, 64};
  cb.s[8]  = {W2, W2c, 2048}; cb.s[9]  = {b2, b2c, 16};
  cb.s[10] = {W4, W4c, 32768}; cb.s[11] = {b4, b4c, 256};
  cb.s[12] = {a1, a1c, 512}; cb.s[13] = {a2, a2c, 512};
  convbatch_kernel<<<dim3(128, 14), 256, 0, stream>>>(cb, flag);

  {
    int n0 = 256 * 3000 / 4, n1 = 256 * 256 / 4, n2 = NSPOT * 256 / 4;
    int tot = n0 + n1 + n2;
    conv3_kernel<<<(tot + 255) / 256, 256, 0, stream>>>(
        gene_freq, GF16, n0, spot_eig, SE16, n1, spot_freq, SF16, n2, flag);
  }

  AsmSet as0 = {c1_Wl, c1_bl, c1_Wr, c1_br, c1p_Wl, c1p_bl, c1p_Wr, c1p_br, Wcat1, bcat1, 256};
  AsmSet as1 = {c3_Wl, c3_bl, c3_Wr, c3_br, c3p_Wl, c3p_bl, c3p_Wr, c3p_br, Wcat2, bcat2, 16};
  assemble2_kernel<<<dim3((256 * 768 + 255) / 256, 2), 256, 0, stream>>>(as0, as1, flag);

  GatSet g1a = {off1, srcs1, attc1,  bc1,  0,   192, 0,  E1N};
  GatSet g1b = {off2, srcs2, attc1p, bc1p, 384, 576, 64, E2N};
  GatSet g3a = {off1, srcs1, attc3,  bc3,  0,   192, 0,  E1N};
  GatSet g3b = {off2, srcs2, attc3p, bc3p, 384, 576, 64, E2N};

  u16* Y;
  u16* XS;
  u16* XG = XGp;
  if (planA){
    u16* AT = (u16*)R;                                       // [20000][3000]
    Y  = (u16*)(R + (size_t)NSPOT * NGENE * 2);              // [20000][768]
    XS = Y + (size_t)NSPOT * 768;                            // [20000][256]

    // transpose gene_eig [3000][20000] -> AT [20000][3000] bf16
    transpose_kernel<<<dim3(313, 47), 256, 0, stream>>>(gene_eig, AT, flag, NGENE, NSPOT);
    // Xg = relu(AT @ GF16^T)  M=20000 N=256 K=3000, 128-row tiles
    gemm_mfma<2, false, true, false, false, true, false, false, false><<<dim3(4, 157), 256, 0, stream>>>(
        AT, GF16, nullptr, XG, nullptr, flag, 0, 0, NSPOT, 256, NGENE, NGENE, NGENE, 256, 0);
  } else {
    Y  = (u16*)R;
    XS = Y + (size_t)NSPOT * 768;
    // Xg directly from K-major gene_eig (f32 ext), gene_freq as B (f32 ext)
    gemm_mfma<2, true, true, true, true, true, false, false, false><<<dim3(4, 157), 256, 0, stream>>>(
        gene_eig, gene_freq, nullptr, XG, nullptr, flag, 0, 0, NSPOT, 256, NGENE, NSPOT, NGENE, 256, 0);
  }

  // Y = SF16 @ Wcat1 + bcat1  M=20000 N=768 K=256
  gemm_mfma<2, false, false, false, false, false, true, false, false><<<dim3(12, 157), 256, 0, stream>>>(
      SF16, Wcat1, bcat1, Y, nullptr, flag, 0, 0, NSPOT, 768, 256, 256, 768, 768, 0);
  // layer 1 GAT (both edge sets, one launch)
  gat2_kernel<<<10000, 256, 0, stream>>>(Y, g1a, g1b, AGG, NSPOT);
  // h2 (-> d_out) and Y2 = h2 @ Wcat2 fused
  h2y2_kernel<<<1250, 256, 0, stream>>>(AGG, W2c, b2c, Wcat2, bcat2, d_out, Y, flag, NSPOT);
  // layer 2 GAT
  gat2_kernel<<<10000, 256, 0, stream>>>(Y, g3a, g3b, AGG, NSPOT);
  // h4 -> d_out (+ bf16 copy to H4B)
  gemm_mfma<2, false, false, false, false, false, true, true, true><<<dim3(4, 157), 256, 0, stream>>>(
      AGG, W4c, b4c, d_out, H4B, flag, 0, OFF_H4, NSPOT, 256, 128, 128, 256, 256, 256);
  // Xs = relu(H4B @ SE16)
  gemm_mfma<2, false, false, false, false, true, false, false, false><<<dim3(4, 157), 256, 0, stream>>>(
      H4B, SE16, nullptr, XS, nullptr, flag, 0, 0, NSPOT, 256, 256, 256, 256, 256, 0);
  cross_attn_kernel<<<5000, 256, 0, stream>>>(XG, XS, a1c, a2c, d_out, flag, NSPOT);

  (void)in_sizes; (void)n_in; (void)out_size; (void)ws_size;
}

// Round 4
// 1024.359 us; speedup vs baseline: 1.3369x; 1.0655x over previous
//
#include <hip/hip_runtime.h>

typedef unsigned short u16;
typedef __attribute__((ext_vector_type(8))) short bf16x8;   // 8 x bf16 bits
typedef __attribute__((ext_vector_type(4))) float floatx4;

#define NSPOT 20000
#define NGENE 3000
#define E1N   640000
#define E2N   320000

// output element offsets (res, lam, h2, h4 concatenated)
#define OFF_RES 0
#define OFF_LAM 5120000
#define OFF_H2  5160000
#define OFF_H4  5480000

__device__ __forceinline__ float b2f(u16 u){
  union { unsigned int i; float f; } v; v.i = ((unsigned int)u) << 16; return v.f;
}
__device__ __forceinline__ u16 f2b(float f){
  union { float f; unsigned int i; } v; v.f = f;
  unsigned int i = v.i;
  return (u16)((i + 0x7FFFu + ((i >> 16) & 1u)) >> 16);
}
__device__ __forceinline__ void stout(void* O, size_t i, float v, int isbf){
  if (isbf) ((u16*)O)[i] = f2b(v); else ((float*)O)[i] = v;
}
__device__ __forceinline__ u16 ldu(const void* p, size_t i, int isbf){
  return isbf ? ((const u16*)p)[i] : f2b(((const float*)p)[i]);
}

// ---------------- dtype sniffer ----------------
__global__ void sniff_kernel(const u16* __restrict__ x, int* __restrict__ flag){
  int lane = threadIdx.x;
  u16 u = x[lane * 2];
  int e = (u >> 7) & 0xFF;
  int sane = (u == 0) || (e >= 0x60 && e <= 0xA0);
  unsigned long long b = __ballot(sane);
  if (lane == 0) flag[0] = (__popcll(b) >= 48) ? 1 : 0;
}

// ---------------- batched small-param convert ----------------
struct ConvSeg { const void* src; u16* dst; int n; };
struct ConvBatch { ConvSeg s[14]; };
__global__ void convbatch_kernel(ConvBatch cb, const int* __restrict__ dflag){
  ConvSeg S = cb.s[blockIdx.y];
  int i = blockIdx.x * 256 + threadIdx.x;
  if (i < S.n) S.dst[i] = ldu(S.src, i, dflag[0]);
}

// fused vectorized convert of the 3 big tensors (each n multiple of 4)
__global__ void conv3_kernel(const void* __restrict__ s0, u16* __restrict__ d0, int n0,
                             const void* __restrict__ s1, u16* __restrict__ d1, int n1,
                             const void* __restrict__ s2, u16* __restrict__ d2, int n2,
                             const int* __restrict__ dflag){
  int i = blockIdx.x * 256 + threadIdx.x;
  const void* src; u16* dst; int local;
  if (i < n0){ src = s0; dst = d0; local = i; }
  else if (i < n0 + n1){ src = s1; dst = d1; local = i - n0; }
  else if (i < n0 + n1 + n2){ src = s2; dst = d2; local = i - n0 - n1; }
  else return;
  size_t b = (size_t)local * 4;
  u16 o[4];
  if (dflag[0]){
    *(uint2*)o = *(const uint2*)((const u16*)src + b);
  } else {
    float4 f = *(const float4*)((const float*)src + b);
    o[0]=f2b(f.x); o[1]=f2b(f.y); o[2]=f2b(f.z); o[3]=f2b(f.w);
  }
  *(uint2*)(dst + b) = *(uint2*)o;
}

// ---------------- CSR build (fused E1+E2 via grid.y / blockIdx.x) ----------------
__global__ void hist2_kernel(const int* __restrict__ dst0, int E0, int* __restrict__ cnt0,
                             const int* __restrict__ dst1, int E1, int* __restrict__ cnt1){
  const int* dst = blockIdx.y ? dst1 : dst0;
  int* cnt = blockIdx.y ? cnt1 : cnt0;
  int E = blockIdx.y ? E1 : E0;
  int e = blockIdx.x * 256 + threadIdx.x;
  if (e < E){ int d = dst[e]; if ((unsigned)d < (unsigned)NSPOT) atomicAdd(&cnt[d], 1); }
}

__global__ void scan2_kernel(const int* __restrict__ c0, int* __restrict__ o0, int* __restrict__ u0,
                             const int* __restrict__ c1, int* __restrict__ o1, int* __restrict__ u1,
                             int n){
  const int* cnt = blockIdx.x ? c1 : c0;
  int* off = blockIdx.x ? o1 : o0;
  int* cur = blockIdx.x ? u1 : u0;
  __shared__ int part[256];
  int tid = threadIdx.x;
  int chunk = (n + 255) / 256;
  int lo = tid * chunk; if (lo > n) lo = n;
  int hi = lo + chunk; if (hi > n) hi = n;
  int s = 0;
  for (int i = lo; i < hi; i++) s += cnt[i];
  part[tid] = s;
  __syncthreads();
  if (tid == 0){
    int run = 0;
    for (int i = 0; i < 256; i++){ int t = part[i]; part[i] = run; run += t; }
  }
  __syncthreads();
  int run = part[tid];
  for (int i = lo; i < hi; i++){ off[i] = run; cur[i] = run; run += cnt[i]; }
  if (hi == n) off[n] = run;
}

__global__ void scatter2_kernel(const int* __restrict__ src0, const int* __restrict__ dst0,
                                int* __restrict__ cur0, int* __restrict__ out0, int E0,
                                const int* __restrict__ src1, const int* __restrict__ dst1,
                                int* __restrict__ cur1, int* __restrict__ out1, int E1){
  const int* src = blockIdx.y ? src1 : src0;
  const int* dst = blockIdx.y ? dst1 : dst0;
  int* cur = blockIdx.y ? cur1 : cur0;
  int* out = blockIdx.y ? out1 : out0;
  int E = blockIdx.y ? E1 : E0;
  int e = blockIdx.x * 256 + threadIdx.x;
  if (e < E){
    int d = dst[e];
    if ((unsigned)d < (unsigned)NSPOT){
      int p = atomicAdd(&cur[d], 1);
      if ((unsigned)p < (unsigned)E) out[p] = src[e];
    }
  }
}

// ---------------- weight concat (both layers in one launch) ----------------
struct AsmSet {
  const void *Wl, *bl, *Wr, *br, *Wlp, *blp, *Wrp, *brp;
  u16* Wcat; u16* bcat; int Kdim;
};
__global__ void assemble2_kernel(AsmSet s0, AsmSet s1, const int* __restrict__ dflag){
  AsmSet S = blockIdx.y ? s1 : s0;
  int isbf = dflag[0];
  int idx = blockIdx.x * 256 + threadIdx.x;
  int total = S.Kdim * 768;
  if (idx < total){
    int k = idx / 768, j = idx % 768;
    int seg = j / 192, jj = j % 192;
    const void* W = (seg == 0) ? S.Wl : (seg == 1) ? S.Wr : (seg == 2) ? S.Wlp : S.Wrp;
    S.Wcat[idx] = ldu(W, (size_t)k * 192 + jj, isbf);
  }
  if (idx < 768){
    int seg = idx / 192, jj = idx % 192;
    const void* b = (seg == 0) ? S.bl : (seg == 1) ? S.br : (seg == 2) ? S.blp : S.brp;
    S.bcat[idx] = ldu(b, jj, isbf);
  }
}

// ---------------- MFMA GEMM (BM = 64*BMI, BN=64, optional split-K via blockIdx.z) ----------------
template<int BMI, bool A_KM, bool B_NK, bool A_EXT, bool B_EXT, bool RELU, bool HAS_BIAS, bool C_OUT, bool C2, bool C_F32>
__global__ __launch_bounds__(256) void gemm_mfma(
    const void* __restrict__ A, const void* __restrict__ B,
    const u16* __restrict__ bias, void* __restrict__ Cp, u16* __restrict__ Cp2,
    const int* __restrict__ dflag, size_t aoff, size_t coff,
    int M, int N, int K, int kchunk, size_t cstride,
    int lda, int ldb, int ldc, int ldc2)
{
  const int isbf = dflag[0];
  constexpr int BM = 64 * BMI, BK = 32, LDA = BK + 8, LDB = BK + 8;
  __shared__ __align__(16) u16 As[BM * LDA];
  __shared__ __align__(16) u16 Bs[64 * LDB];
  const u16*   A16 = (const u16*)A + aoff;
  const float* A32 = (const float*)A + aoff;
  const u16*   B16 = (const u16*)B;
  const float* B32 = (const float*)B;
  auto ldA = [&](size_t i) -> u16 { return (!A_EXT || isbf) ? A16[i] : f2b(A32[i]); };
  auto ldB = [&](size_t i) -> u16 { return (!B_EXT || isbf) ? B16[i] : f2b(B32[i]); };

  int tid = threadIdx.x;
  int lane = tid & 63, w = tid >> 6;
  int m0 = blockIdx.y * BM, n0 = blockIdx.x * 64;
  int kbeg = (int)blockIdx.z * kchunk;
  int kend = (K < kbeg + kchunk) ? K : (kbeg + kchunk);
  floatx4 acc[BMI][4] = {};
  int quad = lane >> 4;
  int nk = (kend - kbeg + BK - 1) / BK;
  for (int kt = 0; kt < nk; kt++){
    int k0 = kbeg + kt * BK;
    // ---- stage A -> As[m][k] ----
    if (!A_KM){
#pragma unroll
      for (int i = 0; i < BMI; i++){
        int id = tid + i * 256;
        int r = id >> 2, c = (id & 3) * 8;
        int gm = m0 + r, gk = k0 + c;
        if (gm < M && gk + 8 <= K){
          if (!A_EXT || isbf){
            *(uint4*)&As[r * LDA + c] = *(const uint4*)(A16 + (size_t)gm * lda + gk);
          } else {
            const float* p = A32 + (size_t)gm * lda + gk;
            float4 f0 = *(const float4*)p, f1 = *(const float4*)(p + 4);
            u16* d = &As[r * LDA + c];
            d[0]=f2b(f0.x); d[1]=f2b(f0.y); d[2]=f2b(f0.z); d[3]=f2b(f0.w);
            d[4]=f2b(f1.x); d[5]=f2b(f1.y); d[6]=f2b(f1.z); d[7]=f2b(f1.w);
          }
        } else {
          for (int e = 0; e < 8; e++)
            As[r * LDA + c + e] = (gm < M && gk + e < K) ? ldA((size_t)gm * lda + gk + e) : (u16)0;
        }
      }
    } else {
#pragma unroll
      for (int i = 0; i < BMI; i++){
        int id = tid + i * 256;
        int kk, rr;
        if (BMI == 2){ kk = id >> 4; rr = (id & 15) * 8; }
        else         { kk = id >> 3; rr = (id & 7) * 8; }
        int gk = k0 + kk, gm = m0 + rr;
        if (gk < K && gm + 8 <= M){
          if (!A_EXT || isbf){
            uint4 v = *(const uint4*)(A16 + (size_t)gk * lda + gm);
            const u16* pv = (const u16*)&v;
#pragma unroll
            for (int e = 0; e < 8; e++) As[(rr + e) * LDA + kk] = pv[e];
          } else {
            const float* p = A32 + (size_t)gk * lda + gm;
            float4 f0 = *(const float4*)p, f1 = *(const float4*)(p + 4);
            As[(rr+0)*LDA+kk]=f2b(f0.x); As[(rr+1)*LDA+kk]=f2b(f0.y);
            As[(rr+2)*LDA+kk]=f2b(f0.z); As[(rr+3)*LDA+kk]=f2b(f0.w);
            As[(rr+4)*LDA+kk]=f2b(f1.x); As[(rr+5)*LDA+kk]=f2b(f1.y);
            As[(rr+6)*LDA+kk]=f2b(f1.z); As[(rr+7)*LDA+kk]=f2b(f1.w);
          }
        } else {
          for (int e = 0; e < 8; e++)
            As[(rr + e) * LDA + kk] = (gk < K && gm + e < M) ? ldA((size_t)gk * lda + gm + e) : (u16)0;
        }
      }
    }
    // ---- stage B -> Bs[n][k] ----
    if (B_NK){
      int r = tid >> 2, c = (tid & 3) * 8;
      int gn = n0 + r, gk = k0 + c;
      if (gn < N && gk + 8 <= K){
        if (!B_EXT || isbf){
          *(uint4*)&Bs[r * LDB + c] = *(const uint4*)(B16 + (size_t)gn * ldb + gk);
        } else {
          const float* p = B32 + (size_t)gn * ldb + gk;
          float4 f0 = *(const float4*)p, f1 = *(const float4*)(p + 4);
          u16* d = &Bs[r * LDB + c];
          d[0]=f2b(f0.x); d[1]=f2b(f0.y); d[2]=f2b(f0.z); d[3]=f2b(f0.w);
          d[4]=f2b(f1.x); d[5]=f2b(f1.y); d[6]=f2b(f1.z); d[7]=f2b(f1.w);
        }
      } else {
        for (int e = 0; e < 8; e++)
          Bs[r * LDB + c + e] = (gn < N && gk + e < K) ? ldB((size_t)gn * ldb + gk + e) : (u16)0;
      }
    } else {
      int kk = tid >> 3, nn = (tid & 7) * 8;
      int gk = k0 + kk, gn = n0 + nn;
      if (gk < K && gn + 8 <= N){
        if (!B_EXT || isbf){
          uint4 v = *(const uint4*)(B16 + (size_t)gk * ldb + gn);
          const u16* pv = (const u16*)&v;
#pragma unroll
          for (int e = 0; e < 8; e++) Bs[(nn + e) * LDB + kk] = pv[e];
        } else {
          const float* p = B32 + (size_t)gk * ldb + gn;
          float4 f0 = *(const float4*)p, f1 = *(const float4*)(p + 4);
          Bs[(nn+0)*LDB+kk]=f2b(f0.x); Bs[(nn+1)*LDB+kk]=f2b(f0.y);
          Bs[(nn+2)*LDB+kk]=f2b(f0.z); Bs[(nn+3)*LDB+kk]=f2b(f0.w);
          Bs[(nn+4)*LDB+kk]=f2b(f1.x); Bs[(nn+5)*LDB+kk]=f2b(f1.y);
          Bs[(nn+6)*LDB+kk]=f2b(f1.z); Bs[(nn+7)*LDB+kk]=f2b(f1.w);
        }
      } else {
        for (int e = 0; e < 8; e++)
          Bs[(nn + e) * LDB + kk] = (gk < K && gn + e < N) ? ldB((size_t)gk * ldb + gn + e) : (u16)0;
      }
    }
    __syncthreads();
    // ---- MFMA ----
    bf16x8 af[BMI];
#pragma unroll
    for (int mi = 0; mi < BMI; mi++)
      af[mi] = *(const bf16x8*)&As[(w * (16 * BMI) + mi * 16 + (lane & 15)) * LDA + quad * 8];
#pragma unroll
    for (int ni = 0; ni < 4; ni++){
      bf16x8 bfr = *(const bf16x8*)&Bs[(ni * 16 + (lane & 15)) * LDB + quad * 8];
#pragma unroll
      for (int mi = 0; mi < BMI; mi++)
        acc[mi][ni] = __builtin_amdgcn_mfma_f32_16x16x32_bf16(af[mi], bfr, acc[mi][ni], 0, 0, 0);
    }
    __syncthreads();
  }
  // ---- epilogue ----
#pragma unroll
  for (int mi = 0; mi < BMI; mi++)
#pragma unroll
    for (int ni = 0; ni < 4; ni++)
#pragma unroll
      for (int r = 0; r < 4; r++){
        int row = m0 + w * (16 * BMI) + mi * 16 + quad * 4 + r;
        int col = n0 + ni * 16 + (lane & 15);
        if (row < M && col < N){
          float v = acc[mi][ni][r];
          if (HAS_BIAS) v += b2f(bias[col]);
          if (RELU) v = fmaxf(v, 0.f);
          size_t ci = coff + (size_t)blockIdx.z * cstride + (size_t)row * ldc + col;
          if (C_F32) ((float*)Cp)[ci] = v;
          else if (!C_OUT) ((u16*)Cp)[ci] = f2b(v);
          else stout(Cp, ci, v, isbf);
          if (C2) Cp2[(size_t)row * ldc2 + col] = f2b(v);
        }
      }
}

// ---------------- reduce 2 split-K partials + ReLU + transpose ----------------
// P: f32 [2][256][20000]; XG out: bf16 [20000][256]
__global__ __launch_bounds__(256) void redtr_kernel(const float* __restrict__ P,
                                                    u16* __restrict__ XG){
  __shared__ float tile[64 * 65];
  int s0 = blockIdx.x * 64;   // spot base (313)
  int c0 = blockIdx.y * 64;   // channel base (4)
  int t = threadIdx.x;
#pragma unroll
  for (int i = 0; i < 4; i++){
    int c = i * 16 + (t >> 4);
    int sp = (t & 15) * 4;
    int gs = s0 + sp;
    size_t base = (size_t)(c0 + c) * NSPOT + gs;
    float v0 = 0.f, v1 = 0.f, v2 = 0.f, v3 = 0.f;
    if (gs + 4 <= NSPOT){
      float4 a = *(const float4*)(P + base);
      float4 b = *(const float4*)(P + (size_t)256 * NSPOT + base);
      v0 = a.x + b.x; v1 = a.y + b.y; v2 = a.z + b.z; v3 = a.w + b.w;
    } else {
      for (int e = 0; e < 4; e++){
        if (gs + e < NSPOT){
          float x = P[base + e] + P[(size_t)256 * NSPOT + base + e];
          if (e == 0) v0 = x; else if (e == 1) v1 = x; else if (e == 2) v2 = x; else v3 = x;
        }
      }
    }
    tile[c * 65 + sp + 0] = fmaxf(v0, 0.f);
    tile[c * 65 + sp + 1] = fmaxf(v1, 0.f);
    tile[c * 65 + sp + 2] = fmaxf(v2, 0.f);
    tile[c * 65 + sp + 3] = fmaxf(v3, 0.f);
  }
  __syncthreads();
#pragma unroll
  for (int i = 0; i < 2; i++){
    int sp = i * 32 + (t >> 3);
    int cc = (t & 7) * 8;
    int gs = s0 + sp;
    if (gs < NSPOT){
      u16 o[8];
#pragma unroll
      for (int e = 0; e < 8; e++) o[e] = f2b(tile[(cc + e) * 65 + sp]);
      *(uint4*)&XG[(size_t)gs * 256 + c0 + cc] = *(uint4*)o;
    }
  }
}

// ---------------- GATv2 aggregation: both edge sets in one launch ----------------
// 8 edges per iteration, 8 lanes per edge (lane = sub*8 + c8, each lane owns
// 8 consecutive channels per head).
struct GatSet {
  const int* off; const int* srcs; const u16* att; const u16* bias;
  int xl_off, xr_off, out_off, E;
};
__global__ __launch_bounds__(256) void gat2_kernel(
    const u16* __restrict__ Y, GatSet SA, GatSet SB,
    u16* __restrict__ aggout, int n)
{
  int half = gridDim.x >> 1;
  int selB = (int)blockIdx.x >= half;
  GatSet S = selB ? SB : SA;
  int bx = blockIdx.x - (selB ? half : 0);
  int wid = (bx * 256 + threadIdx.x) >> 6;
  int lane = threadIdx.x & 63;
  if (wid >= n) return;
  int sub = lane >> 3;          // edge slot within chunk (0..7)
  int cbase = (lane & 7) * 8;   // 8 consecutive channels per head
  const int ldY = 768;
  size_t drow = (size_t)wid * ldY;

  // xr (dst transform) and att, loaded once per dst: 3 heads x 8 channels each
  float xr[3][8], at[3][8];
#pragma unroll
  for (int h = 0; h < 3; h++){
    uint4 vx = *(const uint4*)(Y + drow + S.xr_off + h * 64 + cbase);
    uint4 va = *(const uint4*)(S.att + h * 64 + cbase);
    const u16* px = (const u16*)&vx;
    const u16* pa = (const u16*)&va;
#pragma unroll
    for (int j = 0; j < 8; j++){ xr[h][j] = b2f(px[j]); at[h][j] = b2f(pa[j]); }
  }

  int beg = S.off[wid], end = S.off[wid + 1];
  beg = max(0, min(beg, S.E));
  end = max(beg, min(end, S.E));

  float mh[3] = {-INFINITY, -INFINITY, -INFINITY};
  float lh[3] = {0.f, 0.f, 0.f};
  float ac[3][8] = {};

  // prefetch: gather for chunk 0, src index for chunk 1
  uint4 xa[3] = {};
  int s_b = 0;
  if (beg < end){
    int e0 = beg + sub;
    int s = (e0 < end) ? S.srcs[e0] : 0;
    if ((unsigned)s >= (unsigned)NSPOT) s = 0;
    const u16* p = Y + (size_t)s * ldY + S.xl_off + cbase;
#pragma unroll
    for (int h = 0; h < 3; h++) xa[h] = *(const uint4*)(p + h * 64);
    if (beg + 8 < end){
      int e1 = beg + 8 + sub;
      int s1 = (e1 < end) ? S.srcs[e1] : 0;
      if ((unsigned)s1 >= (unsigned)NSPOT) s1 = 0;
      s_b = s1;
    }
  }

  for (int b = beg; b < end; b += 8){
    uint4 xc[3];
#pragma unroll
    for (int h = 0; h < 3; h++) xc[h] = xa[h];
    bool act = (b + sub) < end;

    // issue gather for chunk b+8 (index already resident), fetch index for b+16
    if (b + 8 < end){
      const u16* p = Y + (size_t)s_b * ldY + S.xl_off + cbase;
#pragma unroll
      for (int h = 0; h < 3; h++) xa[h] = *(const uint4*)(p + h * 64);
      if (b + 16 < end){
        int e2 = b + 16 + sub;
        int s2 = (e2 < end) ? S.srcs[e2] : 0;
        if ((unsigned)s2 >= (unsigned)NSPOT) s2 = 0;
        s_b = s2;
      }
    }

    // partial leaky-dot per lane (8 channels x 3 heads)
    float xl[3][8];
    float t0 = 0.f, t1 = 0.f, t2 = 0.f;
    {
      const u16* p0 = (const u16*)&xc[0];
      const u16* p1 = (const u16*)&xc[1];
      const u16* p2 = (const u16*)&xc[2];
#pragma unroll
      for (int j = 0; j < 8; j++){
        float x0 = b2f(p0[j]); xl[0][j] = x0;
        float u0 = x0 + xr[0][j]; u0 = fmaxf(u0, 0.2f * u0);
        t0 = __builtin_fmaf(at[0][j], u0, t0);
        float x1 = b2f(p1[j]); xl[1][j] = x1;
        float u1 = x1 + xr[1][j]; u1 = fmaxf(u1, 0.2f * u1);
        t1 = __builtin_fmaf(at[1][j], u1, t1);
        float x2 = b2f(p2[j]); xl[2][j] = x2;
        float u2 = x2 + xr[2][j]; u2 = fmaxf(u2, 0.2f * u2);
        t2 = __builtin_fmaf(at[2][j], u2, t2);
      }
    }
    // reduce within each 8-lane subgroup (3 steps, 3 heads interleaved)
#pragma unroll
    for (int d = 1; d < 8; d <<= 1){
      t0 += __shfl_xor(t0, d, 64);
      t1 += __shfl_xor(t1, d, 64);
      t2 += __shfl_xor(t2, d, 64);
    }
    if (act){
      float tt[3] = {t0, t1, t2};
#pragma unroll
      for (int h = 0; h < 3; h++){
        float nm = fmaxf(mh[h], tt[h]);
        if (nm > mh[h]){
          float sc = __expf(mh[h] - nm);   // exp(-inf)=0 on first edge
          lh[h] *= sc;
#pragma unroll
          for (int j = 0; j < 8; j++) ac[h][j] *= sc;
          mh[h] = nm;
        }
        float w = __expf(tt[h] - mh[h]);
        lh[h] += w;
#pragma unroll
        for (int j = 0; j < 8; j++) ac[h][j] = __builtin_fmaf(w, xl[h][j], ac[h][j]);
      }
    }
  }

  // combine the 8 subgroups' online-softmax states (xor 8,16,32 butterfly)
  float o[8] = {};
#pragma unroll
  for (int h = 0; h < 3; h++){
    float gm = fmaxf(mh[h], __shfl_xor(mh[h], 8, 64));
    gm = fmaxf(gm, __shfl_xor(gm, 16, 64));
    gm = fmaxf(gm, __shfl_xor(gm, 32, 64));
    float sc = (mh[h] == -INFINITY) ? 0.f : __expf(mh[h] - gm);
    float L = lh[h] * sc;
    L += __shfl_xor(L, 8, 64);
    L += __shfl_xor(L, 16, 64);
    L += __shfl_xor(L, 32, 64);
    float inv = 1.f / fmaxf(L, 1e-16f);
#pragma unroll
    for (int j = 0; j < 8; j++){
      float a = ac[h][j] * sc;
      a += __shfl_xor(a, 8, 64);
      a += __shfl_xor(a, 16, 64);
      a += __shfl_xor(a, 32, 64);
      o[j] += a * inv;
    }
  }
  if (sub == 0){
    u16 ov[8];
#pragma unroll
    for (int j = 0; j < 8; j++){
      float v = o[j] * (1.f / 3.f) + b2f(S.bias[cbase + j]);
      v = (v > 0.f) ? v : expm1f(v);
      if (!(fabsf(v) < 1e30f)) v = 0.f;
      ov[j] = f2b(v);
    }
    *(uint4*)&aggout[(size_t)wid * 128 + S.out_off + cbase] = *(uint4*)ov;
  }
}

// ---------------- fused h2 = h1@W2+b2 ; Y2 = h2@Wcat2+bcat2 ----------------
__global__ __launch_bounds__(256) void h2y2_kernel(
    const u16* __restrict__ AGG, const u16* __restrict__ W2, const u16* __restrict__ b2,
    const u16* __restrict__ Wcat2, const u16* __restrict__ bcat2,
    void* __restrict__ OUT, u16* __restrict__ Y2,
    const int* __restrict__ dflag, int n){
  __shared__ float w2s[128 * 16];
  __shared__ float as_[16][128];
  __shared__ float h[16][16];
  __shared__ __align__(16) u16 ws_[16 * 768];
  int isbf = dflag[0];
  int tid = threadIdx.x;
  for (int i = tid; i < 128 * 16; i += 256) w2s[i] = b2f(W2[i]);
  for (int i = tid; i < 1536; i += 256) ((uint4*)ws_)[i] = ((const uint4*)Wcat2)[i];
  int m0 = blockIdx.x * 16;
  for (int i = tid; i < 16 * 128; i += 256){
    int r = i >> 7, c = i & 127; int m = m0 + r;
    as_[r][c] = (m < n) ? b2f(AGG[(size_t)m * 128 + c]) : 0.f;
  }
  __syncthreads();
  {
    int r = tid >> 4, j = tid & 15;
    int m = m0 + r;
    float acc = b2f(b2[j]);
    for (int k = 0; k < 128; k++) acc += as_[r][k] * w2s[k * 16 + j];
    h[r][j] = acc;
    if (m < n) stout(OUT, (size_t)OFF_H2 + (size_t)m * 16 + j, acc, isbf);
  }
  __syncthreads();
  // y2 phase: j = tid covers 256 of 768 cols, 3 segments
  int j = tid;
  float acc[16][3];
  float bj0 = b2f(bcat2[j]), bj1 = b2f(bcat2[j + 256]), bj2 = b2f(bcat2[j + 512]);
#pragma unroll
  for (int r = 0; r < 16; r++){ acc[r][0] = bj0; acc[r][1] = bj1; acc[r][2] = bj2; }
  for (int k = 0; k < 16; k++){
    float w0 = b2f(ws_[k * 768 + j]);
    float w1 = b2f(ws_[k * 768 + j + 256]);
    float w2 = b2f(ws_[k * 768 + j + 512]);
#pragma unroll
    for (int r = 0; r < 16; r++){
      float hv = h[r][k];
      acc[r][0] += hv * w0; acc[r][1] += hv * w1; acc[r][2] += hv * w2;
    }
  }
#pragma unroll
  for (int r = 0; r < 16; r++){
    int m = m0 + r;
    if (m < n){
      size_t base = (size_t)m * 768;
      Y2[base + j] = f2b(acc[r][0]);
      Y2[base + j + 256] = f2b(acc[r][1]);
      Y2[base + j + 512] = f2b(acc[r][2]);
    }
  }
}

// ---------------- Cross attention (wave per row) ----------------
__global__ __launch_bounds__(256) void cross_attn_kernel(
    const u16* __restrict__ XG, const u16* __restrict__ XS,
    const u16* __restrict__ a1, const u16* __restrict__ a2,
    void* __restrict__ OUT, const int* __restrict__ dflag, int n){
  int wid = (blockIdx.x * 256 + threadIdx.x) >> 6;
  int lane = threadIdx.x & 63;
  if (wid >= n) return;
  int isbf = dflag[0];
  int c0 = lane * 4;
  size_t base = (size_t)wid * 256 + c0;
  float g[4], s[4];
#pragma unroll
  for (int e = 0; e < 4; e++){ g[e] = b2f(XG[base + e]); s[e] = b2f(XS[base + e]); }
  float p1 = 0.f, p2 = 0.f;
#pragma unroll
  for (int e = 0; e < 4; e++){
    p1 += g[e] * b2f(a1[c0 + e]) + s[e] * b2f(a1[256 + c0 + e]);
    p2 += g[e] * b2f(a2[c0 + e]) + s[e] * b2f(a2[256 + c0 + e]);
  }
#pragma unroll
  for (int d = 32; d > 0; d >>= 1){
    p1 += __shfl_xor(p1, d, 64);
    p2 += __shfl_xor(p2, d, 64);
  }
  float e1 = (p1 > 0.f) ? p1 : 0.2f * p1;
  float e2 = (p2 > 0.f) ? p2 : 0.2f * p2;
  float mx = fmaxf(e1, e2);
  float w1 = __expf(e1 - mx), w2 = __expf(e2 - mx);
  float inv = 1.f / (w1 + w2);
  float l0 = w1 * inv, l1 = w2 * inv;
#pragma unroll
  for (int e = 0; e < 4; e++)
    stout(OUT, (size_t)OFF_RES + base + e, l0 * g[e] + l1 * s[e], isbf);
  if (lane == 0){
    stout(OUT, (size_t)OFF_LAM + (size_t)wid * 2,     l0, isbf);
    stout(OUT, (size_t)OFF_LAM + (size_t)wid * 2 + 1, l1, isbf);
  }
}

extern "C" void kernel_launch(void* const* d_in, const int* in_sizes, int n_in,
                              void* d_out, int out_size, void* d_ws, size_t ws_size,
                              hipStream_t stream) {
  const void* gene_freq = d_in[0];
  const void* gene_eig  = d_in[1];
  const void* spot_freq = d_in[2];
  const void* spot_eig  = d_in[3];
  const int* net1 = (const int*)d_in[4];
  const int* net2 = (const int*)d_in[5];
  const void *c1_Wl=d_in[6],  *c1_bl=d_in[7],  *c1_Wr=d_in[8],  *c1_br=d_in[9],  *c1_att=d_in[10], *c1_b=d_in[11];
  const void *c1p_Wl=d_in[12],*c1p_bl=d_in[13],*c1p_Wr=d_in[14],*c1p_br=d_in[15],*c1p_att=d_in[16],*c1p_b=d_in[17];
  const void *c3_Wl=d_in[18], *c3_bl=d_in[19], *c3_Wr=d_in[20], *c3_br=d_in[21], *c3_att=d_in[22], *c3_b=d_in[23];
  const void *c3p_Wl=d_in[24],*c3p_bl=d_in[25],*c3p_Wr=d_in[26],*c3p_br=d_in[27],*c3p_att=d_in[28],*c3p_b=d_in[29];
  const void *W2=d_in[30], *b2=d_in[31], *W4=d_in[32], *b4=d_in[33], *a1=d_in[34], *a2=d_in[35];

  // ---- workspace carve ----
  char* p0 = (char*)d_ws;
  char* p = p0;
  auto carve = [&](size_t bytes) -> char* {
    char* r = p; p += (bytes + 255) & ~(size_t)255; return r;
  };
  int*   flag  = (int*) carve(256);
  int*   cnt1  = (int*) carve((NSPOT + 2) * 4);
  int*   off1  = (int*) carve((NSPOT + 2) * 4);
  int*   cur1  = (int*) carve((NSPOT + 2) * 4);
  int*   srcs1 = (int*) carve((size_t)E1N * 4);
  int*   cnt2  = (int*) carve((NSPOT + 2) * 4);
  int*   off2  = (int*) carve((NSPOT + 2) * 4);
  int*   cur2  = (int*) carve((NSPOT + 2) * 4);
  int*   srcs2 = (int*) carve((size_t)E2N * 4);
  u16*   Wcat1 = (u16*) carve(256 * 768 * 2);
  u16*   bcat1 = (u16*) carve(2048);
  u16*   Wcat2 = (u16*) carve(16 * 768 * 2);
  u16*   bcat2 = (u16*) carve(2048);
  u16*   attc1  = (u16*)carve(192 * 2);
  u16*   attc1p = (u16*)carve(192 * 2);
  u16*   attc3  = (u16*)carve(192 * 2);
  u16*   attc3p = (u16*)carve(192 * 2);
  u16*   bc1  = (u16*)carve(64 * 2);
  u16*   bc1p = (u16*)carve(64 * 2);
  u16*   bc3  = (u16*)carve(64 * 2);
  u16*   bc3p = (u16*)carve(64 * 2);
  u16*   W2c  = (u16*)carve(2048 * 2);
  u16*   b2c  = (u16*)carve(16 * 2);
  u16*   W4c  = (u16*)carve(32768 * 2);
  u16*   b4c  = (u16*)carve(256 * 2);
  u16*   a1c  = (u16*)carve(512 * 2);
  u16*   a2c  = (u16*)carve(512 * 2);
  u16*   GF16 = (u16*) carve((size_t)256 * 3000 * 2);
  u16*   SE16 = (u16*) carve((size_t)256 * 256 * 2);
  u16*   SF16 = (u16*) carve((size_t)NSPOT * 256 * 2);   // spot_freq bf16
  u16*   H4B  = (u16*) carve((size_t)NSPOT * 256 * 2);   // bf16 copy of h4
  u16*   AGG  = (u16*) carve((size_t)NSPOT * 128 * 2);
  u16*   XG   = (u16*) carve((size_t)NSPOT * 256 * 2);   // Xg [20000][256] bf16
  char*  R    = carve((size_t)2 * 256 * NSPOT * 4);      // region: P f32 [2][256][20000]
  // aliases within R (stream-ordered reuse: P dead after redtr_kernel)
  float* Pbuf = (float*)R;
  u16*   Y    = (u16*)R;                                  // [20000][768] after redtr
  u16*   XS   = (u16*)(R + (size_t)NSPOT * 768 * 2);      // [20000][256] (fits: 30.72+10.24 < 40.96+pad)

  // --- prologue ---
  sniff_kernel<<<1, 64, 0, stream>>>((const u16*)spot_freq, flag);
  hipMemsetAsync(cnt1, 0, NSPOT * 4, stream);
  hipMemsetAsync(cnt2, 0, NSPOT * 4, stream);
  hist2_kernel<<<dim3((E1N + 255) / 256, 2), 256, 0, stream>>>(
      net1 + E1N, E1N, cnt1, net2 + E2N, E2N, cnt2);
  scan2_kernel<<<2, 256, 0, stream>>>(cnt1, off1, cur1, cnt2, off2, cur2, NSPOT);
  scatter2_kernel<<<dim3((E1N + 255) / 256, 2), 256, 0, stream>>>(
      net1, net1 + E1N, cur1, srcs1, E1N, net2, net2 + E2N, cur2, srcs2, E2N);

  ConvBatch cb;
  cb.s[0]  = {c1_att,  attc1,  192}; cb.s[1]  = {c1p_att, attc1p, 192};
  cb.s[2]  = {c3_att,  attc3,  192}; cb.s[3]  = {c3p_att, attc3p, 192};
  cb.s[4]  = {c1_b, bc1, 64}; cb.s[5]  = {c1p_b, bc1p, 64};
  cb.s[6]  = {c3_b, bc3, 64}; cb.s[7]  = {c3p_b, bc3p, 64};
  cb.s[8]  = {W2, W2c, 2048}; cb.s[9]  = {b2, b2c, 16};
  cb.s[10] = {W4, W4c, 32768}; cb.s[11] = {b4, b4c, 256};
  cb.s[12] = {a1, a1c, 512}; cb.s[13] = {a2, a2c, 512};
  convbatch_kernel<<<dim3(128, 14), 256, 0, stream>>>(cb, flag);

  {
    int n0 = 256 * 3000 / 4, n1 = 256 * 256 / 4, n2 = NSPOT * 256 / 4;
    int tot = n0 + n1 + n2;
    conv3_kernel<<<(tot + 255) / 256, 256, 0, stream>>>(
        gene_freq, GF16, n0, spot_eig, SE16, n1, spot_freq, SF16, n2, flag);
  }

  AsmSet as0 = {c1_Wl, c1_bl, c1_Wr, c1_br, c1p_Wl, c1p_bl, c1p_Wr, c1p_br, Wcat1, bcat1, 256};
  AsmSet as1 = {c3_Wl, c3_bl, c3_Wr, c3_br, c3p_Wl, c3p_bl, c3p_Wr, c3p_br, Wcat2, bcat2, 16};
  assemble2_kernel<<<dim3((256 * 768 + 255) / 256, 2), 256, 0, stream>>>(as0, as1, flag);

  GatSet g1a = {off1, srcs1, attc1,  bc1,  0,   192, 0,  E1N};
  GatSet g1b = {off2, srcs2, attc1p, bc1p, 384, 576, 64, E2N};
  GatSet g3a = {off1, srcs1, attc3,  bc3,  0,   192, 0,  E1N};
  GatSet g3b = {off2, srcs2, attc3p, bc3p, 384, 576, 64, E2N};

  // XgT partials: P[z] = GF16[256][3000] @ gene_eig[3000][20000] over K-chunk z
  // A: bf16 [M=256][K], !A_KM. B: gene_eig native [K][N], B_NK=false, B_EXT (f32/bf16).
  gemm_mfma<2, false, false, false, true, false, false, false, false, true>
      <<<dim3(313, 2, 2), 256, 0, stream>>>(
      GF16, gene_eig, nullptr, Pbuf, nullptr, flag, 0, 0,
      256, NSPOT, NGENE, 1504, (size_t)256 * NSPOT, NGENE, NSPOT, NSPOT, 0);
  // Xg = relu(P0+P1)^T -> [20000][256] bf16
  redtr_kernel<<<dim3(313, 4), 256, 0, stream>>>(Pbuf, XG);

  // Y = SF16 @ Wcat1 + bcat1  M=20000 N=768 K=256  (P now dead; Y aliases R)
  gemm_mfma<2, false, false, false, false, false, true, false, false, false>
      <<<dim3(12, 157), 256, 0, stream>>>(
      SF16, Wcat1, bcat1, Y, nullptr, flag, 0, 0,
      NSPOT, 768, 256, 256, 0, 256, 768, 768, 0);
  // layer 1 GAT (both edge sets, one launch)
  gat2_kernel<<<10000, 256, 0, stream>>>(Y, g1a, g1b, AGG, NSPOT);
  // h2 (-> d_out) and Y2 = h2 @ Wcat2 fused
  h2y2_kernel<<<1250, 256, 0, stream>>>(AGG, W2c, b2c, Wcat2, bcat2, d_out, Y, flag, NSPOT);
  // layer 2 GAT
  gat2_kernel<<<10000, 256, 0, stream>>>(Y, g3a, g3b, AGG, NSPOT);
  // h4 -> d_out (+ bf16 copy to H4B); BMI=1 for 2x blocks (latency-bound, K=128)
  gemm_mfma<1, false, false, false, false, false, true, true, true, false>
      <<<dim3(4, 313), 256, 0, stream>>>(
      AGG, W4c, b4c, d_out, H4B, flag, 0, OFF_H4,
      NSPOT, 256, 128, 128, 0, 128, 256, 256, 256);
  // Xs = relu(H4B @ SE16); BMI=1
  gemm_mfma<1, false, false, false, false, true, false, false, false, false>
      <<<dim3(4, 313), 256, 0, stream>>>(
      H4B, SE16, nullptr, XS, nullptr, flag, 0, 0,
      NSPOT, 256, 256, 256, 0, 256, 256, 256, 0);
  cross_attn_kernel<<<5000, 256, 0, stream>>>(XG, XS, a1c, a2c, d_out, flag, NSPOT);

  (void)in_sizes; (void)n_in; (void)out_size; (void)ws_size;
}